// Round 16
// baseline (1377.362 us; speedup 1.0000x reference)
//
#include <hip/hip_runtime.h>
#include <math.h>

// ---------------------------------------------------------------------------
// SlotAttention fused forward. MFMA (bf16) attention path (r13 k_attn core).
//   k_setup: all weight prep in one launch.
//   k_attn (2048 blocks) with FUSED V/A reduction: last block per batch
//   (threadfence+atomic counter) reduces vpart/apart inline -> no k_vred.
//   Tail: k_gates + fused k_mlp; k_prep zeroes cnt for the next k_attn.
// ---------------------------------------------------------------------------

#define NKV   4096
#define DD    256
#define HQN   32
#define EPSR  1e-8f

// workspace layout (float offsets)
#define WS_V      0                     // 262144
#define WS_A0     262144                // 1024
#define WS_A1     263168                // 1024
#define WS_C0     264192                // 1024
#define WS_C1     265216                // 1024
#define WS_SLOTA  266240                // 65536
#define WS_SLOTB  331776                // 65536
#define WS_WQT    397312                // 65536 fp32 Wq^T
#define WS_WPGXH  462848                // 393216 (wp_bf 131072f | gxh [256][1536])
#define WS_WFT    856064                // 393216 uints: WfoldT2 [512][768]
#define WS_WHHT   1249280               // 98304 uints:  WhhT2   [128][768]
#define WS_W1T    1347584               // 131072 uints: W1T2    [128][1024]
#define WS_W2T    1478656               // 131072 uints: W2T2    [512][256]
#define WS_RS     1609728               // 131072 fp32 rs per token
#define WS_RM     1740800               // 131072 fp32 rm per token
#define WS_VPART  1871872               // 8388608 uints: Vpart bf16x2, 32MB
#define WS_APART  10260480              // 262144 fp32: apart[2048 blk][128]
#define WS_CNT    10522624              // 32 ints

typedef float f32x4 __attribute__((ext_vector_type(4)));
typedef short s16x8 __attribute__((ext_vector_type(8)));
typedef int   v2i   __attribute__((ext_vector_type(2)));

__device__ __forceinline__ unsigned bfr(float f) {
    unsigned u = __float_as_uint(f);
    return (u + 0x7fffu + ((u >> 16) & 1u)) >> 16;
}
__device__ __forceinline__ unsigned pk2(float lo, float hi) {
    return bfr(lo) | (bfr(hi) << 16);
}
__device__ __forceinline__ float bf2f(unsigned short us) {
    return __uint_as_float((unsigned)us << 16);
}
__device__ __forceinline__ float bflo(unsigned u) { return __uint_as_float(u << 16); }
__device__ __forceinline__ float bfhi(unsigned u) { return __uint_as_float(u & 0xffff0000u); }

__device__ __forceinline__ v2i tr_read(unsigned addr) {
    v2i d;
    asm volatile("ds_read_b64_tr_b16 %0, %1" : "=v"(d) : "v"(addr));
    return d;
}
__device__ __forceinline__ s16x8 mk_frag(v2i a, v2i b) {
    union { int i[4]; s16x8 s; } u;
    u.i[0] = a.x; u.i[1] = a.y; u.i[2] = b.x; u.i[3] = b.y;
    return u.s;
}

// ---------------------------------------------------------------------------
// Fused weight prep. grid 1600.
__global__ __launch_bounds__(256) void k_setup(
    const float* __restrict__ Wq, const float* __restrict__ Wih,
    const float* __restrict__ Wv, const float* __restrict__ Whh,
    const float* __restrict__ W1, const float* __restrict__ W2,
    float* __restrict__ wqt, unsigned* __restrict__ WfT2,
    unsigned* __restrict__ WhhT2, unsigned* __restrict__ W1T2,
    unsigned* __restrict__ W2T2)
{
    const int blk = blockIdx.x;
    const int t = threadIdx.x;
    if (blk < 64) {
        __shared__ float tile[32][33];
        int bx = (blk & 7) * 32, by = (blk >> 3) * 32;
        int tx = t & 31, ty = t >> 5;
        #pragma unroll
        for (int k = 0; k < 32; k += 8)
            tile[ty + k][tx] = Wq[(size_t)(by + ty + k) * 256 + bx + tx];
        __syncthreads();
        #pragma unroll
        for (int k = 0; k < 32; k += 8)
            wqt[(size_t)(bx + ty + k) * 256 + by + tx] = tile[tx][ty + k];
    } else if (blk < 832) {
        const int c = blk - 64;
        __shared__ float wr[256];
        wr[t] = Wih[(size_t)c * 256 + t];
        __syncthreads();
        const float2* wv2 = (const float2*)Wv;
        #pragma unroll
        for (int pp = 0; pp < 2; ++pp) {
            int P = pp * 256 + t;
            int h = P >> 7, p = P & 127;
            float f0 = 0.f, f1 = 0.f;
            #pragma unroll 8
            for (int d = 0; d < 64; ++d) {
                float a = wr[h * 64 + d];
                float2 v = wv2[(size_t)(h * 64 + d) * 128 + p];
                f0 = fmaf(a, v.x, f0); f1 = fmaf(a, v.y, f1);
            }
            WfT2[(size_t)P * 768 + c] = pk2(f0, f1);
        }
    } else if (blk < 960) {
        const int c2 = blk - 832;
        #pragma unroll
        for (int q = 0; q < 3; ++q) {
            int r = q * 256 + t;
            WhhT2[(size_t)c2 * 768 + r] = pk2(Whh[(size_t)r * 256 + 2 * c2],
                                              Whh[(size_t)r * 256 + 2 * c2 + 1]);
        }
    } else if (blk < 1088) {
        const int c2 = blk - 960;
        #pragma unroll
        for (int q = 0; q < 4; ++q) {
            int r = q * 256 + t;
            W1T2[(size_t)c2 * 1024 + r] = pk2(W1[(size_t)r * 256 + 2 * c2],
                                              W1[(size_t)r * 256 + 2 * c2 + 1]);
        }
    } else {
        const int c2 = blk - 1088;
        W2T2[(size_t)c2 * 256 + t] = pk2(W2[(size_t)t * 1024 + 2 * c2],
                                         W2[(size_t)t * 1024 + 2 * c2 + 1]);
    }
}

// ---------------------------------------------------------------------------
// Merged slot prep: grid (32 b, 4 h). Also zeroes cnt[b] for the next k_attn.
__global__ __launch_bounds__(256) void k_prep(
    const float* __restrict__ slots, const float* __restrict__ g_s, const float* __restrict__ b_s,
    const float* __restrict__ wqt, const float* __restrict__ Wk,
    const float* __restrict__ g_in, const float* __restrict__ b_in,
    unsigned short* __restrict__ wp_bf, float* __restrict__ c0_g, float* __restrict__ c1_g,
    int* __restrict__ cnt)
{
    __shared__ float s_lds[2048];
    __shared__ float qs[512];
    __shared__ float redc[4096];
    const int t = threadIdx.x;
    const int b = blockIdx.x, h = blockIdx.y;
    const int lane = t & 63, w = t >> 6;
    const float LNS = 0.125f * 1.44269504f;

    if (h == 0 && t == 0) cnt[b] = 0;

    for (int r = w; r < 8; r += 4) {
        const float4 v = ((const float4*)(slots + ((size_t)b * 8 + r) * 256))[lane];
        float s0 = v.x + v.y + v.z + v.w;
        float s1 = v.x * v.x + v.y * v.y + v.z * v.z + v.w * v.w;
        #pragma unroll
        for (int o = 32; o >= 1; o >>= 1) { s0 += __shfl_xor(s0, o, 64); s1 += __shfl_xor(s1, o, 64); }
        float m = s0 * (1.f / 256.f);
        float rs = rsqrtf(s1 * (1.f / 256.f) - m * m + 1e-5f);
        float4 gg = ((const float4*)g_s)[lane];
        float4 bb = ((const float4*)b_s)[lane];
        float4 nn;
        nn.x = (v.x - m) * rs * gg.x + bb.x;
        nn.y = (v.y - m) * rs * gg.y + bb.y;
        nn.z = (v.z - m) * rs * gg.z + bb.z;
        nn.w = (v.w - m) * rs * gg.w + bb.w;
        ((float4*)(s_lds + r * 256))[lane] = nn;
    }
    __syncthreads();

    {
        const int qi0 = t >> 6, d = t & 63;
        float a0 = 0.f, a1 = 0.f;
        #pragma unroll 8
        for (int j = 0; j < 256; ++j) {
            float wv = wqt[j * 256 + h * 64 + d];
            a0 = fmaf(s_lds[qi0 * 256 + j], wv, a0);
            a1 = fmaf(s_lds[(qi0 + 4) * 256 + j], wv, a1);
        }
        qs[qi0 * 64 + d] = a0;
        qs[(qi0 + 4) * 64 + d] = a1;
    }
    __syncthreads();

    float a2[8];
    #pragma unroll
    for (int qi = 0; qi < 8; ++qi) a2[qi] = 0.f;
    #pragma unroll 4
    for (int d = 0; d < 64; ++d) {
        float wv = Wk[(size_t)(h * 64 + d) * 256 + t];
        #pragma unroll
        for (int qi = 0; qi < 8; ++qi) a2[qi] = fmaf(qs[qi * 64 + d], wv, a2[qi]);
    }
    const float gv = g_in[t], bv = b_in[t];
    #pragma unroll
    for (int qi = 0; qi < 8; ++qi) {
        float kv = LNS * a2[qi];
        float we = kv * gv;
        wp_bf[((size_t)b * HQN + h * 8 + qi) * 256 + t] = (unsigned short)bfr(we);
        redc[qi * 256 + t] = we;
        redc[2048 + qi * 256 + t] = kv * bv;
    }
    __syncthreads();
    #pragma unroll
    for (int rep = 0; rep < 2; ++rep) {
        int r = w * 2 + rep;
        float sv1 = redc[r * 256 + lane] + redc[r * 256 + 64 + lane] +
                    redc[r * 256 + 128 + lane] + redc[r * 256 + 192 + lane];
        float sv0 = redc[2048 + r * 256 + lane] + redc[2048 + r * 256 + 64 + lane] +
                    redc[2048 + r * 256 + 128 + lane] + redc[2048 + r * 256 + 192 + lane];
        #pragma unroll
        for (int o = 32; o >= 1; o >>= 1) {
            sv1 += __shfl_xor(sv1, o, 64);
            sv0 += __shfl_xor(sv0, o, 64);
        }
        if (lane == 0) {
            c1_g[b * 32 + h * 8 + r] = sv1;
            c0_g[b * 32 + h * 8 + r] = sv0;
        }
    }
}

// ---------------------------------------------------------------------------
// k_attn helpers
__device__ __forceinline__ void load_x(const float* __restrict__ inp, int b, int n0,
                                       int tok_s, int seg8, float4* ld) {
    const float4* row4 = (const float4*)(inp + ((size_t)b * NKV + n0 + tok_s) * 256);
    #pragma unroll
    for (int u = 0; u < 8; ++u) ld[u] = row4[(u >> 2) * 32 + seg8 * 4 + (u & 3)];
}

__device__ __forceinline__ void pack_x(const float4* ld, char* dst, int tok_s, int seg8) {
    #pragma unroll
    for (int c = 0; c < 2; ++c) {
        int nt = seg8 + 8 * c;
        #pragma unroll
        for (int h = 0; h < 2; ++h) {
            float4 fa = ld[c * 4 + h * 2], fb = ld[c * 4 + h * 2 + 1];
            uint4 pk;
            pk.x = pk2(fa.x, fa.y); pk.y = pk2(fa.z, fa.w);
            pk.z = pk2(fb.x, fb.y); pk.w = pk2(fb.z, fb.w);
            *(uint4*)(dst + nt * 1040 + tok_s * 32 + h * 16) = pk;
        }
    }
}

__device__ __forceinline__ void calc_stats(const float4* ld, float* sb,
                                           float* __restrict__ rs_g, float* __restrict__ rm_g,
                                           int b, int n0, int tok_s, int seg8) {
    float s0 = 0.f, s1 = 0.f;
    #pragma unroll
    for (int u = 0; u < 8; ++u) {
        float4 v = ld[u];
        s0 += v.x + v.y + v.z + v.w;
        s1 = fmaf(v.x, v.x, s1); s1 = fmaf(v.y, v.y, s1);
        s1 = fmaf(v.z, v.z, s1); s1 = fmaf(v.w, v.w, s1);
    }
    s0 += __shfl_xor(s0, 1, 64); s1 += __shfl_xor(s1, 1, 64);
    s0 += __shfl_xor(s0, 2, 64); s1 += __shfl_xor(s1, 2, 64);
    s0 += __shfl_xor(s0, 4, 64); s1 += __shfl_xor(s1, 4, 64);
    float m  = s0 * (1.f / 256.f);
    float rs = rsqrtf(s1 * (1.f / 256.f) - m * m + 1e-5f);
    if (seg8 == 0) {
        sb[tok_s] = rs;
        sb[32 + tok_s] = rs * m;
        rs_g[b * 4096 + n0 + tok_s] = rs;
        rm_g[b * 4096 + n0 + tok_s] = rs * m;
    }
}

// V+A reduction slice (one y in [0,16), 2 hq rows) for batch b.
template<int KBMAX>
__device__ void vred_body(int b, int y, int t,
    const unsigned* __restrict__ vpart, const float* __restrict__ apart,
    float* __restrict__ V_g, float* __restrict__ A0_g, float* __restrict__ A1_g)
{
    const int hq = y * 2 + (t >> 7);
    const int tl = t & 127;
    const unsigned* p = vpart + ((size_t)(b * KBMAX) * 32 + hq) * 128 + tl;
    float lo = 0.f, hi = 0.f;
    #pragma unroll 8
    for (int kb = 0; kb < KBMAX; ++kb) {
        unsigned u = p[(size_t)kb * 4096];
        lo += bflo(u); hi += bfhi(u);
    }
    const int jp = tl >> 4, li = tl & 15;
    float* vo = V_g + ((size_t)b * 32 + hq) * 256 + jp * 32 + li;
    vo[0]  = lo;
    vo[16] = hi;

    if (y == 0 && t < 64) {
        float s = 0.f;
        const float* ap = apart + (size_t)(b * KBMAX) * 128 + t;
        #pragma unroll 8
        for (int kb = 0; kb < KBMAX; ++kb)
            s += ap[(size_t)kb * 128] + ap[(size_t)kb * 128 + 64];
        if (t < 32) A0_g[b * 32 + t] = s;
        else        A1_g[b * 32 + t - 32] = s;
    }
}

// ---------------------------------------------------------------------------
// Main fused MFMA pass (r13 core). grid (64, 32), NC=2 chunks of 32 tokens.
// Epilogue: partial stores + threadfence + per-batch counter; the LAST block
// of each batch reduces that batch's vpart/apart inline (no k_vred dispatch).
template<int NC, int STATS, int WVIS>
__global__ __launch_bounds__(256) void k_attn(
    const float* __restrict__ inp, const unsigned short* __restrict__ wp_bf,
    const float* __restrict__ c0_g, const float* __restrict__ c1_g,
    unsigned* __restrict__ vpart, float* __restrict__ apart,
    float* __restrict__ rs_g, float* __restrict__ rm_g,
    float* __restrict__ V_g, float* __restrict__ A0_g, float* __restrict__ A1_g,
    int* __restrict__ cnt,
    float* __restrict__ out_vis, float* __restrict__ out_temp)
{
    constexpr int KBMAX = 128 / NC;
    __shared__ unsigned short xb[8320];
    __shared__ unsigned short wl[8192];
    __shared__ unsigned short pt[1024];
    __shared__ float stats[2][64];
    __shared__ int isLast;

    const int t = threadIdx.x;
    const int l = t & 63, w = t >> 6;
    const int g = l >> 4, li = l & 15;
    const int b = blockIdx.y, kb = blockIdx.x;

    char* xbB = (char*)xb;
    char* wlB = (char*)wl;
    char* ptB = (char*)pt;
    const int tok_s = t >> 3, seg8 = t & 7;
    const int cbase = kb * NC;

    {
        const uint4* wp4 = (const uint4*)wp_bf + ((size_t)b * 8192 + (t >> 3) * 256 + (t & 7) * 32) / 8;
        const int hq = t >> 3, sg = t & 7;
        #pragma unroll
        for (int q = 0; q < 4; ++q) {
            uint4 v = wp4[q];
            *(uint4*)(wlB + hq * 512 + (((sg * 4 + q) ^ (hq & 7)) * 16)) = v;
        }
    }

    const int Mt = w & 1, Nt = w >> 1;
    const int hqB = Nt * 16 + li;
    const int hq0 = li, hq1 = 16 + li;
    const float c0h0 = c0_g[b * 32 + hq0], c1h0 = c1_g[b * 32 + hq0];
    const float c0h1 = c0_g[b * 32 + hq1], c1h1 = c1_g[b * 32 + hq1];
    const int MtV = w >> 1, ntb = (w & 1) * 8;
    const int hqA = MtV * 16 + li;

    f32x4 av[8];
    #pragma unroll
    for (int u = 0; u < 8; ++u) av[u] = (f32x4){0.f, 0.f, 0.f, 0.f};
    float A0acc = 0.f, A1acc = 0.f;

    const unsigned xbase = (unsigned)(uintptr_t)xbB;

    {
        float4 ldA[8];
        load_x(inp, b, cbase * 32, tok_s, seg8, ldA);
        if (STATS) {
            calc_stats(ldA, &stats[0][0], rs_g, rm_g, b, cbase * 32, tok_s, seg8);
        } else {
            if (t < 32) stats[0][t] = rs_g[b * 4096 + cbase * 32 + t];
            else if (t < 64) stats[0][t] = rm_g[b * 4096 + cbase * 32 + t - 32];
        }
        pack_x(ldA, xbB, tok_s, seg8);
    }
    __syncthreads();   // A

    #pragma unroll
    for (int ci = 0; ci < NC; ++ci) {
        const int cur = ci & 1, nxt = cur ^ 1;
        const int n0 = (cbase + ci) * 32;

        float4 ldN[8];
        if (ci < NC - 1) load_x(inp, b, n0 + 32, tok_s, seg8, ldN);
        __builtin_amdgcn_sched_barrier(0);

        f32x4 accS0 = (f32x4){0.f, 0.f, 0.f, 0.f};
        f32x4 accS1 = (f32x4){0.f, 0.f, 0.f, 0.f};
        __builtin_amdgcn_s_setprio(1);
        #pragma unroll
        for (int kk = 0; kk < 8; ++kk) {
            s16x8 af = *(const s16x8*)(xbB + (kk * 2 + (g >> 1)) * 1040 +
                                       (Mt * 16 + li) * 32 + (g & 1) * 16);
            s16x8 bf0 = *(const s16x8*)(wlB + hq0 * 512 + (((kk * 4 + g) ^ (hq0 & 7)) * 16));
            s16x8 bf1 = *(const s16x8*)(wlB + hq1 * 512 + (((kk * 4 + g) ^ (hq1 & 7)) * 16));
            accS0 = __builtin_amdgcn_mfma_f32_16x16x32_bf16(af, bf0, accS0, 0, 0, 0);
            accS1 = __builtin_amdgcn_mfma_f32_16x16x32_bf16(af, bf1, accS1, 0, 0, 0);
        }
        __builtin_amdgcn_s_setprio(0);

        float aaW[4], rsv[4], rmv[4];
        #pragma unroll
        for (int r = 0; r < 4; ++r) {
            int tokr = Mt * 16 + g * 4 + r;
            rsv[r] = stats[cur][tokr];
            rmv[r] = stats[cur][32 + tokr];
            float lg0 = fmaf(rsv[r], accS0[r], fmaf(-rmv[r], c1h0, c0h0));
            float lg1 = fmaf(rsv[r], accS1[r], fmaf(-rmv[r], c1h1, c0h1));
            float v = fmaxf(lg0, lg1);
            v = fmaxf(v, __shfl_xor(v, 1, 64));
            v = fmaxf(v, __shfl_xor(v, 2, 64));
            v = fmaxf(v, __shfl_xor(v, 4, 64));
            v = fmaxf(v, __shfl_xor(v, 8, 64));
            float ex0 = exp2f(lg0 - v);
            float ex1 = exp2f(lg1 - v);
            float s = ex0 + ex1;
            s += __shfl_xor(s, 1, 64);
            s += __shfl_xor(s, 2, 64);
            s += __shfl_xor(s, 4, 64);
            s += __shfl_xor(s, 8, 64);
            float inv = 1.f / s;
            float aw = (Nt ? ex1 : ex0) * inv;
            A0acc += aw;
            A1acc = fmaf(aw, rmv[r], A1acc);
            aaW[r] = aw * rsv[r];
        }
        {
            uint2 pw;
            pw.x = pk2(aaW[0], aaW[1]);
            pw.y = pk2(aaW[2], aaW[3]);
            int tokb = Mt * 16 + g * 4;
            int slot = (tokb >> 3) ^ ((hqB >> 1) & 3);
            *(uint2*)(ptB + hqB * 64 + slot * 16 + (tokb & 7) * 2) = pw;
        }
        __syncthreads();   // D

        if (WVIS) {
            int tk = t >> 3, q = t & 7;
            float sv = 0.f;
            #pragma unroll
            for (int h = 0; h < 4; ++h) {
                int hq = h * 8 + q;
                int slot = (tk >> 3) ^ ((hq >> 1) & 3);
                sv += bf2f(*(const unsigned short*)(ptB + hq * 64 + slot * 16 + (tk & 7) * 2));
            }
            float vv = sv / stats[cur][tk];
            size_t o = ((size_t)b * NKV + n0 + tk) * 8 + q;
            out_vis[o] = vv; out_temp[o] = vv;
        }

        if (ci < NC - 1) {
            if (STATS) {
                calc_stats(ldN, &stats[nxt][0], rs_g, rm_g, b, n0 + 32, tok_s, seg8);
            } else {
                if (t < 32) stats[nxt][t] = rs_g[b * 4096 + n0 + 32 + t];
                else if (t < 64) stats[nxt][t] = rm_g[b * 4096 + n0 + 32 + t - 32];
            }
        }

        {
            s16x8 pa = *(const s16x8*)(ptB + hqA * 64 + ((g ^ ((hqA >> 1) & 3)) * 16));
            unsigned abase = xbase + g * 256 + li * 8;
            v2i t0a = tr_read(abase + (ntb + 0) * 1040);
            v2i t0b = tr_read(abase + (ntb + 0) * 1040 + 128);
            v2i t1a = tr_read(abase + (ntb + 1) * 1040);
            v2i t1b = tr_read(abase + (ntb + 1) * 1040 + 128);
            v2i t2a = tr_read(abase + (ntb + 2) * 1040);
            v2i t2b = tr_read(abase + (ntb + 2) * 1040 + 128);
            v2i t3a = tr_read(abase + (ntb + 3) * 1040);
            v2i t3b = tr_read(abase + (ntb + 3) * 1040 + 128);
            asm volatile("s_waitcnt lgkmcnt(0)" ::: "memory");
            __builtin_amdgcn_sched_barrier(0);
            __builtin_amdgcn_s_setprio(1);
            av[0] = __builtin_amdgcn_mfma_f32_16x16x32_bf16(pa, mk_frag(t0a, t0b), av[0], 0, 0, 0);
            av[1] = __builtin_amdgcn_mfma_f32_16x16x32_bf16(pa, mk_frag(t1a, t1b), av[1], 0, 0, 0);
            av[2] = __builtin_amdgcn_mfma_f32_16x16x32_bf16(pa, mk_frag(t2a, t2b), av[2], 0, 0, 0);
            av[3] = __builtin_amdgcn_mfma_f32_16x16x32_bf16(pa, mk_frag(t3a, t3b), av[3], 0, 0, 0);
            __builtin_amdgcn_s_setprio(0);
            v2i t4a = tr_read(abase + (ntb + 4) * 1040);
            v2i t4b = tr_read(abase + (ntb + 4) * 1040 + 128);
            v2i t5a = tr_read(abase + (ntb + 5) * 1040);
            v2i t5b = tr_read(abase + (ntb + 5) * 1040 + 128);
            v2i t6a = tr_read(abase + (ntb + 6) * 1040);
            v2i t6b = tr_read(abase + (ntb + 6) * 1040 + 128);
            v2i t7a = tr_read(abase + (ntb + 7) * 1040);
            v2i t7b = tr_read(abase + (ntb + 7) * 1040 + 128);
            asm volatile("s_waitcnt lgkmcnt(0)" ::: "memory");
            __builtin_amdgcn_sched_barrier(0);
            __builtin_amdgcn_s_setprio(1);
            av[4] = __builtin_amdgcn_mfma_f32_16x16x32_bf16(pa, mk_frag(t4a, t4b), av[4], 0, 0, 0);
            av[5] = __builtin_amdgcn_mfma_f32_16x16x32_bf16(pa, mk_frag(t5a, t5b), av[5], 0, 0, 0);
            av[6] = __builtin_amdgcn_mfma_f32_16x16x32_bf16(pa, mk_frag(t6a, t6b), av[6], 0, 0, 0);
            av[7] = __builtin_amdgcn_mfma_f32_16x16x32_bf16(pa, mk_frag(t7a, t7b), av[7], 0, 0, 0);
            __builtin_amdgcn_s_setprio(0);
        }
        __syncthreads();   // E

        if (ci < NC - 1) {
            pack_x(ldN, xbB, tok_s, seg8);
            __syncthreads();   // A
        }
    }

    // ---- epilogue: partial stores ----
    A0acc += __shfl_xor(A0acc, 16, 64); A0acc += __shfl_xor(A0acc, 32, 64);
    A1acc += __shfl_xor(A1acc, 16, 64); A1acc += __shfl_xor(A1acc, 32, 64);
    const size_t blk = (size_t)b * KBMAX + kb;
    if (g == 0) {
        apart[blk * 128 + Mt * 64 + hqB] = A0acc;
        apart[blk * 128 + Mt * 64 + 32 + hqB] = A1acc;
    }
    {
        #pragma unroll
        for (int r = 0; r < 4; ++r) {
            int hq = MtV * 16 + g * 4 + r;
            unsigned* vp = vpart + (blk * 32 + hq) * 128 + li;
            #pragma unroll
            for (int ip = 0; ip < 4; ++ip) {
                unsigned u = pk2(av[2 * ip][r], av[2 * ip + 1][r]);
                int jp = (ntb >> 1) + ip;
                vp[jp * 16] = u;
            }
        }
    }

    // ---- fused reduction: last block of this batch reduces vpart/apart ----
    __threadfence();
    __syncthreads();
    if (t == 0) {
        int old = atomicAdd(&cnt[b], 1);
        isLast = (old == KBMAX - 1) ? 1 : 0;
    }
    __syncthreads();
    if (isLast) {
        __threadfence();   // acquire: see all other blocks' partials
        #pragma unroll 1
        for (int y = 0; y < 16; ++y)
            vred_body<KBMAX>(b, y, t, vpart, apart, V_g, A0_g, A1_g);
    }
}

// ---------------------------------------------------------------------------
// gx | gh GEMMs. grid (6, 64). chunk-0 blocks zero slot_nxt.
__global__ __launch_bounds__(256) void k_gates(
    const float* __restrict__ V_g, const float* __restrict__ A0_g,
    const float* __restrict__ A1_g,
    const float* __restrict__ g_in, const float* __restrict__ b_in,
    const float* __restrict__ slot_cur,
    const unsigned* __restrict__ WfT2, const unsigned* __restrict__ WhhT2,
    float* __restrict__ gxh, float* __restrict__ slot_nxt)
{
    __shared__ __align__(16) float aT[1024 * 4];
    const int t = threadIdx.x;
    const int rg = blockIdx.y;
    const int chunk = blockIdx.x;
    const int row0 = rg * 4;
    float acc0 = 0.f, acc1 = 0.f, acc2 = 0.f, acc3 = 0.f;

    if (chunk == 0) {
        #pragma unroll
        for (int rr = 0; rr < 4; ++rr)
            slot_nxt[(size_t)(row0 + rr) * 256 + t] = 0.f;
    }

    if (chunk < 3) {
        const int b = rg >> 1, qi0 = (rg & 1) * 4;
        const float gt = g_in[t], bt = b_in[t];
        #pragma unroll
        for (int kk = 0; kk < 4; ++kk) {
            float4 y4;
            #pragma unroll
            for (int rr = 0; rr < 4; ++rr) {
                int hq = kk * 8 + qi0 + rr;
                float A0 = A0_g[b * 32 + hq], A1 = A1_g[b * 32 + hq];
                float den = A0 + EPSR * (float)NKV;
                float vv = V_g[((size_t)b * 32 + hq) * 256 + t];
                float yv = (gt * (vv - A1) + bt * A0) / den;
                ((float*)&y4)[rr] = yv;
            }
            *(float4*)(aT + (kk * 256 + t) * 4) = y4;
        }
        __syncthreads();
        const unsigned* wp = WfT2 + chunk * 256 + t;
        #pragma unroll 4
        for (int k2 = 0; k2 < 512; ++k2) {
            unsigned wv = wp[(size_t)k2 * 768];
            float w0 = bflo(wv), w1 = bfhi(wv);
            float4 a0 = *(const float4*)(aT + 8 * k2);
            float4 a1 = *(const float4*)(aT + 8 * k2 + 4);
            acc0 = fmaf(a0.x, w0, acc0); acc0 = fmaf(a1.x, w1, acc0);
            acc1 = fmaf(a0.y, w0, acc1); acc1 = fmaf(a1.y, w1, acc1);
            acc2 = fmaf(a0.z, w0, acc2); acc2 = fmaf(a1.z, w1, acc2);
            acc3 = fmaf(a0.w, w0, acc3); acc3 = fmaf(a1.w, w1, acc3);
        }
        float* go = gxh + (size_t)row0 * 1536 + chunk * 256 + t;
        go[0] = acc0; go[1536] = acc1; go[3072] = acc2; go[4608] = acc3;
    } else {
        const int gc = chunk - 3;
        {
            float4 y4;
            #pragma unroll
            for (int rr = 0; rr < 4; ++rr)
                ((float*)&y4)[rr] = slot_cur[(size_t)(row0 + rr) * 256 + t];
            *(float4*)(aT + t * 4) = y4;
        }
        __syncthreads();
        const unsigned* wp = WhhT2 + gc * 256 + t;
        #pragma unroll 4
        for (int k2 = 0; k2 < 128; ++k2) {
            unsigned wv = wp[(size_t)k2 * 768];
            float w0 = bflo(wv), w1 = bfhi(wv);
            float4 a0 = *(const float4*)(aT + 8 * k2);
            float4 a1 = *(const float4*)(aT + 8 * k2 + 4);
            acc0 = fmaf(a0.x, w0, acc0); acc0 = fmaf(a1.x, w1, acc0);
            acc1 = fmaf(a0.y, w0, acc1); acc1 = fmaf(a1.y, w1, acc1);
            acc2 = fmaf(a0.z, w0, acc2); acc2 = fmaf(a1.z, w1, acc2);
            acc3 = fmaf(a0.w, w0, acc3); acc3 = fmaf(a1.w, w1, acc3);
        }
        float* go = gxh + (size_t)row0 * 1536 + 768 + gc * 256 + t;
        go[0] = acc0; go[1536] = acc1; go[3072] = acc2; go[4608] = acc3;
    }
}

// ---------------------------------------------------------------------------
// Fused GRU elementwise + LN + MLP(W1,relu,W2) with h1 in LDS. grid (4, 64).
__global__ __launch_bounds__(256) void k_mlp(
    const float* __restrict__ gxh, const float* __restrict__ slot_cur,
    const float* __restrict__ bih, const float* __restrict__ bhh,
    const float* __restrict__ gm, const float* __restrict__ bm,
    const unsigned* __restrict__ W1T2, const float* __restrict__ b1,
    const unsigned* __restrict__ W2T2, const float* __restrict__ b2,
    float* __restrict__ slot_nxt)
{
    __shared__ __align__(16) float mT[1024];
    __shared__ float sm_l[4][256];
    __shared__ float h1_l[4][256];
    __shared__ float lnst[8];
    const int t = threadIdx.x;
    const int rg = blockIdx.y, chunk = blockIdx.x;
    const int row0 = rg * 4;
    const int lane = t & 63, w = t >> 6;

    const float bi0 = bih[t], bi1 = bih[256 + t], bi2 = bih[512 + t];
    const float bh0 = bhh[t], bh1 = bhh[256 + t], bh2 = bhh[512 + t];
    float smid[4];
    #pragma unroll
    for (int rr = 0; rr < 4; ++rr) {
        const float* gr = gxh + (size_t)(row0 + rr) * 1536;
        float gx0 = gr[t], gx1 = gr[256 + t], gx2 = gr[512 + t];
        float gh0 = gr[768 + t], gh1 = gr[1024 + t], gh2 = gr[1280 + t];
        float spv = slot_cur[(size_t)(row0 + rr) * 256 + t];
        float r = 1.f / (1.f + __expf(-(gx0 + bi0 + gh0 + bh0)));
        float z = 1.f / (1.f + __expf(-(gx1 + bi1 + gh1 + bh1)));
        float n = tanhf(gx2 + bi2 + r * (gh2 + bh2));
        smid[rr] = (1.f - z) * n + z * spv;
        sm_l[rr][t] = smid[rr];
    }
    __syncthreads();
    {
        float4 v = *(const float4*)(&sm_l[w][lane * 4]);
        float s0 = v.x + v.y + v.z + v.w;
        float s1 = v.x * v.x + v.y * v.y + v.z * v.z + v.w * v.w;
        #pragma unroll
        for (int o = 32; o >= 1; o >>= 1) { s0 += __shfl_xor(s0, o, 64); s1 += __shfl_xor(s1, o, 64); }
        if (lane == 0) {
            float mu = s0 * (1.f / 256.f);
            lnst[w * 2] = mu;
            lnst[w * 2 + 1] = rsqrtf(s1 * (1.f / 256.f) - mu * mu + 1e-5f);
        }
    }
    __syncthreads();
    {
        const float gmt = gm[t], bmt = bm[t];
        float4 m4;
        #pragma unroll
        for (int rr = 0; rr < 4; ++rr)
            ((float*)&m4)[rr] = (smid[rr] - lnst[rr * 2]) * lnst[rr * 2 + 1] * gmt + bmt;
        *(float4*)(mT + t * 4) = m4;
    }
    __syncthreads();

    {
        float acc0 = 0.f, acc1 = 0.f, acc2 = 0.f, acc3 = 0.f;
        const unsigned* wp = W1T2 + chunk * 256 + t;
        #pragma unroll 4
        for (int k2 = 0; k2 < 128; ++k2) {
            unsigned wv = wp[(size_t)k2 * 1024];
            float w0 = bflo(wv), w1 = bfhi(wv);
            float4 a0 = *(const float4*)(mT + 8 * k2);
            float4 a1 = *(const float4*)(mT + 8 * k2 + 4);
            acc0 = fmaf(a0.x, w0, acc0); acc0 = fmaf(a1.x, w1, acc0);
            acc1 = fmaf(a0.y, w0, acc1); acc1 = fmaf(a1.y, w1, acc1);
            acc2 = fmaf(a0.z, w0, acc2); acc2 = fmaf(a1.z, w1, acc2);
            acc3 = fmaf(a0.w, w0, acc3); acc3 = fmaf(a1.w, w1, acc3);
        }
        const float b1t = b1[chunk * 256 + t];
        h1_l[0][t] = fmaxf(acc0 + b1t, 0.f);
        h1_l[1][t] = fmaxf(acc1 + b1t, 0.f);
        h1_l[2][t] = fmaxf(acc2 + b1t, 0.f);
        h1_l[3][t] = fmaxf(acc3 + b1t, 0.f);
    }
    __syncthreads();

    {
        float o0 = 0.f, o1 = 0.f, o2 = 0.f, o3 = 0.f;
        const unsigned* wp = W2T2 + (size_t)(chunk * 128) * 256 + t;
        #pragma unroll 4
        for (int k2 = 0; k2 < 128; ++k2) {
            unsigned wv = wp[(size_t)k2 * 256];
            float w0 = bflo(wv), w1 = bfhi(wv);
            float a00 = h1_l[0][2 * k2], a01 = h1_l[0][2 * k2 + 1];
            float a10 = h1_l[1][2 * k2], a11 = h1_l[1][2 * k2 + 1];
            float a20 = h1_l[2][2 * k2], a21 = h1_l[2][2 * k2 + 1];
            float a30 = h1_l[3][2 * k2], a31 = h1_l[3][2 * k2 + 1];
            o0 = fmaf(a00, w0, o0); o0 = fmaf(a01, w1, o0);
            o1 = fmaf(a10, w0, o1); o1 = fmaf(a11, w1, o1);
            o2 = fmaf(a20, w0, o2); o2 = fmaf(a21, w1, o2);
            o3 = fmaf(a30, w0, o3); o3 = fmaf(a31, w1, o3);
        }
        const float b2t = b2[t];
        float p0 = o0 + ((chunk == 0) ? smid[0] + b2t : 0.f);
        float p1 = o1 + ((chunk == 0) ? smid[1] + b2t : 0.f);
        float p2 = o2 + ((chunk == 0) ? smid[2] + b2t : 0.f);
        float p3 = o3 + ((chunk == 0) ? smid[3] + b2t : 0.f);
        atomicAdd(slot_nxt + (size_t)(row0 + 0) * 256 + t, p0);
        atomicAdd(slot_nxt + (size_t)(row0 + 1) * 256 + t, p1);
        atomicAdd(slot_nxt + (size_t)(row0 + 2) * 256 + t, p2);
        atomicAdd(slot_nxt + (size_t)(row0 + 3) * 256 + t, p3);
    }
}

// ---------------------------------------------------------------------------
extern "C" void kernel_launch(void* const* d_in, const int* in_sizes, int n_in,
                              void* d_out, int out_size, void* d_ws, size_t ws_size,
                              hipStream_t stream) {
    const float* inp     = (const float*)d_in[0];
    const float* slots0  = (const float*)d_in[1];
    const float* ln_in_g = (const float*)d_in[2];
    const float* ln_in_b = (const float*)d_in[3];
    const float* ln_s_g  = (const float*)d_in[4];
    const float* ln_s_b  = (const float*)d_in[5];
    const float* ln_m_g  = (const float*)d_in[6];
    const float* ln_m_b  = (const float*)d_in[7];
    const float* Wq  = (const float*)d_in[8];
    const float* Wk  = (const float*)d_in[9];
    const float* Wv  = (const float*)d_in[10];
    const float* Wih = (const float*)d_in[11];
    const float* Whh = (const float*)d_in[12];
    const float* bih = (const float*)d_in[13];
    const float* bhh = (const float*)d_in[14];
    const float* W1  = (const float*)d_in[15];
    const float* b1  = (const float*)d_in[16];
    const float* W2  = (const float*)d_in[17];
    const float* b2  = (const float*)d_in[18];

    float* ws = (float*)d_ws;
    float* V_g   = ws + WS_V;
    float* A0_g  = ws + WS_A0;
    float* A1_g  = ws + WS_A1;
    float* c0_g  = ws + WS_C0;
    float* c1_g  = ws + WS_C1;
    float* slotA = ws + WS_SLOTA;
    float* slotB = ws + WS_SLOTB;
    float* wqt   = ws + WS_WQT;
    float* gxh   = ws + WS_WPGXH;
    unsigned short* wp_bf = (unsigned short*)(ws + WS_WPGXH);
    unsigned* WfT2  = (unsigned*)(ws + WS_WFT);
    unsigned* WhhT2 = (unsigned*)(ws + WS_WHHT);
    unsigned* W1T2  = (unsigned*)(ws + WS_W1T);
    unsigned* W2T2  = (unsigned*)(ws + WS_W2T);
    float* rs_g  = ws + WS_RS;
    float* rm_g  = ws + WS_RM;
    unsigned* vpart = (unsigned*)(ws + WS_VPART);
    float* apart = ws + WS_APART;
    int* cnt = (int*)(ws + WS_CNT);

    float* out_slots = (float*)d_out;
    float* out_vis   = out_slots + 32 * 8 * 256;
    float* out_temp  = out_vis + 32 * 4096 * 8;

    k_setup<<<1600, 256, 0, stream>>>(Wq, Wih, Wv, Whh, W1, W2,
                                      wqt, WfT2, WhhT2, W1T2, W2T2);

    for (int it = 0; it < 3; ++it) {
        const float* cur = (it == 0) ? slots0 : ((it == 1) ? slotB : slotA);
        float* nxt = (it == 0) ? slotB : ((it == 1) ? slotA : out_slots);
        k_prep<<<dim3(32, 4), 256, 0, stream>>>(cur, ln_s_g, ln_s_b, wqt, Wk,
                                                ln_in_g, ln_in_b, wp_bf, c0_g, c1_g, cnt);
        if (it == 0)
            k_attn<2, 1, 0><<<dim3(64, 32), 256, 0, stream>>>(
                inp, wp_bf, c0_g, c1_g, vpart, apart, rs_g, rm_g,
                V_g, A0_g, A1_g, cnt, out_vis, out_temp);
        else if (it == 1)
            k_attn<2, 0, 0><<<dim3(64, 32), 256, 0, stream>>>(
                inp, wp_bf, c0_g, c1_g, vpart, apart, rs_g, rm_g,
                V_g, A0_g, A1_g, cnt, out_vis, out_temp);
        else
            k_attn<2, 0, 1><<<dim3(64, 32), 256, 0, stream>>>(
                inp, wp_bf, c0_g, c1_g, vpart, apart, rs_g, rm_g,
                V_g, A0_g, A1_g, cnt, out_vis, out_temp);
        k_gates<<<dim3(6, 64), 256, 0, stream>>>(
            V_g, A0_g, A1_g, ln_in_g, ln_in_b, cur, WfT2, WhhT2, gxh, nxt);
        k_mlp<<<dim3(4, 64), 256, 0, stream>>>(
            gxh, cur, bih, bhh, ln_m_g, ln_m_b, W1T2, b1, W2T2, b2, nxt);
    }
}

// Round 17
// 430.704 us; speedup vs baseline: 3.1979x; 3.1979x over previous
//
#include <hip/hip_runtime.h>
#include <math.h>

// ---------------------------------------------------------------------------
// SlotAttention fused forward. MFMA (bf16) attention path (r13 k_attn, proven).
//   Single fused k_setup (Wq^T | Wfold | WhhT2 | W1T2 | W2T2) in one launch.
//   iter0 reads slots0 directly (no copy); iter2 writes out_slots directly.
//   A0/A1: per-block partials (apart), V partials bf16 (vpart) -> k_vred.
//   GRU/MLP: gx = yflat @ Wfold^T; k_gates + fused k_mlp.
// This is the r14 configuration (measured 429 us), reverted after r15/r16
// showed grid.sync (~130us/sync) and per-block __threadfence (~170us agg)
// are catastrophic on the 8-XCD part. Kernel-boundary sync (~9us) is cheap.
// ---------------------------------------------------------------------------

#define NKV   4096
#define DD    256
#define HQN   32
#define EPSR  1e-8f

// workspace layout (float offsets)
#define WS_V      0                     // 262144
#define WS_A0     262144                // 1024
#define WS_A1     263168                // 1024
#define WS_C0     264192                // 1024
#define WS_C1     265216                // 1024
#define WS_SLOTA  266240                // 65536
#define WS_SLOTB  331776                // 65536
#define WS_WQT    397312                // 65536 fp32 Wq^T
#define WS_WPGXH  462848                // 393216 (wp_bf 131072f | gxh [256][1536])
#define WS_WFT    856064                // 393216 uints: WfoldT2 [512][768]
#define WS_WHHT   1249280               // 98304 uints:  WhhT2   [128][768]
#define WS_W1T    1347584               // 131072 uints: W1T2    [128][1024]
#define WS_W2T    1478656               // 131072 uints: W2T2    [512][256]
#define WS_RS     1609728               // 131072 fp32 rs per token
#define WS_RM     1740800               // 131072 fp32 rm per token
#define WS_VPART  1871872               // 8388608 uints: Vpart bf16x2, 32MB
#define WS_APART  10260480              // 262144 fp32: apart[2048 blk][128]

typedef float f32x4 __attribute__((ext_vector_type(4)));
typedef short s16x8 __attribute__((ext_vector_type(8)));
typedef int   v2i   __attribute__((ext_vector_type(2)));

__device__ __forceinline__ unsigned bfr(float f) {
    unsigned u = __float_as_uint(f);
    return (u + 0x7fffu + ((u >> 16) & 1u)) >> 16;
}
__device__ __forceinline__ unsigned pk2(float lo, float hi) {
    return bfr(lo) | (bfr(hi) << 16);
}
__device__ __forceinline__ float bf2f(unsigned short us) {
    return __uint_as_float((unsigned)us << 16);
}
__device__ __forceinline__ float bflo(unsigned u) { return __uint_as_float(u << 16); }
__device__ __forceinline__ float bfhi(unsigned u) { return __uint_as_float(u & 0xffff0000u); }

__device__ __forceinline__ v2i tr_read(unsigned addr) {
    v2i d;
    asm volatile("ds_read_b64_tr_b16 %0, %1" : "=v"(d) : "v"(addr));
    return d;
}
__device__ __forceinline__ s16x8 mk_frag(v2i a, v2i b) {
    union { int i[4]; s16x8 s; } u;
    u.i[0] = a.x; u.i[1] = a.y; u.i[2] = b.x; u.i[3] = b.y;
    return u.s;
}

// ---------------------------------------------------------------------------
// Fused weight prep. grid 1600:
//   [0,64):    Wq -> wqt (32x32 tiled transpose)
//   [64,832):  Wfold row c (Wv folded into Wih)
//   [832,960): Whh -> WhhT2 pack
//   [960,1088): W1 -> W1T2 pack
//   [1088,1600): W2 -> W2T2 pack
__global__ __launch_bounds__(256) void k_setup(
    const float* __restrict__ Wq, const float* __restrict__ Wih,
    const float* __restrict__ Wv, const float* __restrict__ Whh,
    const float* __restrict__ W1, const float* __restrict__ W2,
    float* __restrict__ wqt, unsigned* __restrict__ WfT2,
    unsigned* __restrict__ WhhT2, unsigned* __restrict__ W1T2,
    unsigned* __restrict__ W2T2)
{
    const int blk = blockIdx.x;
    const int t = threadIdx.x;
    if (blk < 64) {
        __shared__ float tile[32][33];
        int bx = (blk & 7) * 32, by = (blk >> 3) * 32;
        int tx = t & 31, ty = t >> 5;
        #pragma unroll
        for (int k = 0; k < 32; k += 8)
            tile[ty + k][tx] = Wq[(size_t)(by + ty + k) * 256 + bx + tx];
        __syncthreads();
        #pragma unroll
        for (int k = 0; k < 32; k += 8)
            wqt[(size_t)(bx + ty + k) * 256 + by + tx] = tile[tx][ty + k];
    } else if (blk < 832) {
        const int c = blk - 64;
        __shared__ float wr[256];
        wr[t] = Wih[(size_t)c * 256 + t];
        __syncthreads();
        const float2* wv2 = (const float2*)Wv;
        #pragma unroll
        for (int pp = 0; pp < 2; ++pp) {
            int P = pp * 256 + t;
            int h = P >> 7, p = P & 127;
            float f0 = 0.f, f1 = 0.f;
            #pragma unroll 8
            for (int d = 0; d < 64; ++d) {
                float a = wr[h * 64 + d];
                float2 v = wv2[(size_t)(h * 64 + d) * 128 + p];
                f0 = fmaf(a, v.x, f0); f1 = fmaf(a, v.y, f1);
            }
            WfT2[(size_t)P * 768 + c] = pk2(f0, f1);
        }
    } else if (blk < 960) {
        const int c2 = blk - 832;
        #pragma unroll
        for (int q = 0; q < 3; ++q) {
            int r = q * 256 + t;
            WhhT2[(size_t)c2 * 768 + r] = pk2(Whh[(size_t)r * 256 + 2 * c2],
                                              Whh[(size_t)r * 256 + 2 * c2 + 1]);
        }
    } else if (blk < 1088) {
        const int c2 = blk - 960;
        #pragma unroll
        for (int q = 0; q < 4; ++q) {
            int r = q * 256 + t;
            W1T2[(size_t)c2 * 1024 + r] = pk2(W1[(size_t)r * 256 + 2 * c2],
                                              W1[(size_t)r * 256 + 2 * c2 + 1]);
        }
    } else {
        const int c2 = blk - 1088;
        W2T2[(size_t)c2 * 256 + t] = pk2(W2[(size_t)t * 1024 + 2 * c2],
                                         W2[(size_t)t * 1024 + 2 * c2 + 1]);
    }
}

// ---------------------------------------------------------------------------
// Merged slot prep: grid (32 b, 4 h).
__global__ __launch_bounds__(256) void k_prep(
    const float* __restrict__ slots, const float* __restrict__ g_s, const float* __restrict__ b_s,
    const float* __restrict__ wqt, const float* __restrict__ Wk,
    const float* __restrict__ g_in, const float* __restrict__ b_in,
    unsigned short* __restrict__ wp_bf, float* __restrict__ c0_g, float* __restrict__ c1_g)
{
    __shared__ float s_lds[2048];
    __shared__ float qs[512];
    __shared__ float redc[4096];
    const int t = threadIdx.x;
    const int b = blockIdx.x, h = blockIdx.y;
    const int lane = t & 63, w = t >> 6;
    const float LNS = 0.125f * 1.44269504f;

    for (int r = w; r < 8; r += 4) {
        const float4 v = ((const float4*)(slots + ((size_t)b * 8 + r) * 256))[lane];
        float s0 = v.x + v.y + v.z + v.w;
        float s1 = v.x * v.x + v.y * v.y + v.z * v.z + v.w * v.w;
        #pragma unroll
        for (int o = 32; o >= 1; o >>= 1) { s0 += __shfl_xor(s0, o, 64); s1 += __shfl_xor(s1, o, 64); }
        float m = s0 * (1.f / 256.f);
        float rs = rsqrtf(s1 * (1.f / 256.f) - m * m + 1e-5f);
        float4 gg = ((const float4*)g_s)[lane];
        float4 bb = ((const float4*)b_s)[lane];
        float4 nn;
        nn.x = (v.x - m) * rs * gg.x + bb.x;
        nn.y = (v.y - m) * rs * gg.y + bb.y;
        nn.z = (v.z - m) * rs * gg.z + bb.z;
        nn.w = (v.w - m) * rs * gg.w + bb.w;
        ((float4*)(s_lds + r * 256))[lane] = nn;
    }
    __syncthreads();

    {
        const int qi0 = t >> 6, d = t & 63;
        float a0 = 0.f, a1 = 0.f;
        #pragma unroll 8
        for (int j = 0; j < 256; ++j) {
            float wv = wqt[j * 256 + h * 64 + d];
            a0 = fmaf(s_lds[qi0 * 256 + j], wv, a0);
            a1 = fmaf(s_lds[(qi0 + 4) * 256 + j], wv, a1);
        }
        qs[qi0 * 64 + d] = a0;
        qs[(qi0 + 4) * 64 + d] = a1;
    }
    __syncthreads();

    float a2[8];
    #pragma unroll
    for (int qi = 0; qi < 8; ++qi) a2[qi] = 0.f;
    #pragma unroll 4
    for (int d = 0; d < 64; ++d) {
        float wv = Wk[(size_t)(h * 64 + d) * 256 + t];
        #pragma unroll
        for (int qi = 0; qi < 8; ++qi) a2[qi] = fmaf(qs[qi * 64 + d], wv, a2[qi]);
    }
    const float gv = g_in[t], bv = b_in[t];
    #pragma unroll
    for (int qi = 0; qi < 8; ++qi) {
        float kv = LNS * a2[qi];
        float we = kv * gv;
        wp_bf[((size_t)b * HQN + h * 8 + qi) * 256 + t] = (unsigned short)bfr(we);
        redc[qi * 256 + t] = we;
        redc[2048 + qi * 256 + t] = kv * bv;
    }
    __syncthreads();
    #pragma unroll
    for (int rep = 0; rep < 2; ++rep) {
        int r = w * 2 + rep;
        float sv1 = redc[r * 256 + lane] + redc[r * 256 + 64 + lane] +
                    redc[r * 256 + 128 + lane] + redc[r * 256 + 192 + lane];
        float sv0 = redc[2048 + r * 256 + lane] + redc[2048 + r * 256 + 64 + lane] +
                    redc[2048 + r * 256 + 128 + lane] + redc[2048 + r * 256 + 192 + lane];
        #pragma unroll
        for (int o = 32; o >= 1; o >>= 1) {
            sv1 += __shfl_xor(sv1, o, 64);
            sv0 += __shfl_xor(sv0, o, 64);
        }
        if (lane == 0) {
            c1_g[b * 32 + h * 8 + r] = sv1;
            c0_g[b * 32 + h * 8 + r] = sv0;
        }
    }
}

// ---------------------------------------------------------------------------
// k_attn helpers
__device__ __forceinline__ void load_x(const float* __restrict__ inp, int b, int n0,
                                       int tok_s, int seg8, float4* ld) {
    const float4* row4 = (const float4*)(inp + ((size_t)b * NKV + n0 + tok_s) * 256);
    #pragma unroll
    for (int u = 0; u < 8; ++u) ld[u] = row4[(u >> 2) * 32 + seg8 * 4 + (u & 3)];
}

__device__ __forceinline__ void pack_x(const float4* ld, char* dst, int tok_s, int seg8) {
    #pragma unroll
    for (int c = 0; c < 2; ++c) {
        int nt = seg8 + 8 * c;
        #pragma unroll
        for (int h = 0; h < 2; ++h) {
            float4 fa = ld[c * 4 + h * 2], fb = ld[c * 4 + h * 2 + 1];
            uint4 pk;
            pk.x = pk2(fa.x, fa.y); pk.y = pk2(fa.z, fa.w);
            pk.z = pk2(fb.x, fb.y); pk.w = pk2(fb.z, fb.w);
            *(uint4*)(dst + nt * 1040 + tok_s * 32 + h * 16) = pk;
        }
    }
}

__device__ __forceinline__ void calc_stats(const float4* ld, float* sb,
                                           float* __restrict__ rs_g, float* __restrict__ rm_g,
                                           int b, int n0, int tok_s, int seg8) {
    float s0 = 0.f, s1 = 0.f;
    #pragma unroll
    for (int u = 0; u < 8; ++u) {
        float4 v = ld[u];
        s0 += v.x + v.y + v.z + v.w;
        s1 = fmaf(v.x, v.x, s1); s1 = fmaf(v.y, v.y, s1);
        s1 = fmaf(v.z, v.z, s1); s1 = fmaf(v.w, v.w, s1);
    }
    s0 += __shfl_xor(s0, 1, 64); s1 += __shfl_xor(s1, 1, 64);
    s0 += __shfl_xor(s0, 2, 64); s1 += __shfl_xor(s1, 2, 64);
    s0 += __shfl_xor(s0, 4, 64); s1 += __shfl_xor(s1, 4, 64);
    float m  = s0 * (1.f / 256.f);
    float rs = rsqrtf(s1 * (1.f / 256.f) - m * m + 1e-5f);
    if (seg8 == 0) {
        sb[tok_s] = rs;
        sb[32 + tok_s] = rs * m;
        rs_g[b * 4096 + n0 + tok_s] = rs;
        rm_g[b * 4096 + n0 + tok_s] = rs * m;
    }
}

// ---------------------------------------------------------------------------
// Main fused MFMA pass (r13 structure, proven). grid (64, 32), NC=2.
template<int NC, int STATS, int WVIS>
__global__ __launch_bounds__(256) void k_attn(
    const float* __restrict__ inp, const unsigned short* __restrict__ wp_bf,
    const float* __restrict__ c0_g, const float* __restrict__ c1_g,
    unsigned* __restrict__ vpart, float* __restrict__ apart,
    float* __restrict__ rs_g, float* __restrict__ rm_g,
    float* __restrict__ out_vis, float* __restrict__ out_temp)
{
    constexpr int KBMAX = 128 / NC;
    __shared__ unsigned short xb[8320];
    __shared__ unsigned short wl[8192];
    __shared__ unsigned short pt[1024];
    __shared__ float stats[2][64];

    const int t = threadIdx.x;
    const int l = t & 63, w = t >> 6;
    const int g = l >> 4, li = l & 15;
    const int b = blockIdx.y, kb = blockIdx.x;

    char* xbB = (char*)xb;
    char* wlB = (char*)wl;
    char* ptB = (char*)pt;
    const int tok_s = t >> 3, seg8 = t & 7;
    const int cbase = kb * NC;

    {
        const uint4* wp4 = (const uint4*)wp_bf + ((size_t)b * 8192 + (t >> 3) * 256 + (t & 7) * 32) / 8;
        const int hq = t >> 3, sg = t & 7;
        #pragma unroll
        for (int q = 0; q < 4; ++q) {
            uint4 v = wp4[q];
            *(uint4*)(wlB + hq * 512 + (((sg * 4 + q) ^ (hq & 7)) * 16)) = v;
        }
    }

    const int Mt = w & 1, Nt = w >> 1;
    const int hqB = Nt * 16 + li;
    const int hq0 = li, hq1 = 16 + li;
    const float c0h0 = c0_g[b * 32 + hq0], c1h0 = c1_g[b * 32 + hq0];
    const float c0h1 = c0_g[b * 32 + hq1], c1h1 = c1_g[b * 32 + hq1];
    const int MtV = w >> 1, ntb = (w & 1) * 8;
    const int hqA = MtV * 16 + li;

    f32x4 av[8];
    #pragma unroll
    for (int u = 0; u < 8; ++u) av[u] = (f32x4){0.f, 0.f, 0.f, 0.f};
    float A0acc = 0.f, A1acc = 0.f;

    const unsigned xbase = (unsigned)(uintptr_t)xbB;

    {
        float4 ldA[8];
        load_x(inp, b, cbase * 32, tok_s, seg8, ldA);
        if (STATS) {
            calc_stats(ldA, &stats[0][0], rs_g, rm_g, b, cbase * 32, tok_s, seg8);
        } else {
            if (t < 32) stats[0][t] = rs_g[b * 4096 + cbase * 32 + t];
            else if (t < 64) stats[0][t] = rm_g[b * 4096 + cbase * 32 + t - 32];
        }
        pack_x(ldA, xbB, tok_s, seg8);
    }
    __syncthreads();   // A

    #pragma unroll
    for (int ci = 0; ci < NC; ++ci) {
        const int cur = ci & 1, nxt = cur ^ 1;
        const int n0 = (cbase + ci) * 32;

        float4 ldN[8];
        if (ci < NC - 1) load_x(inp, b, n0 + 32, tok_s, seg8, ldN);
        __builtin_amdgcn_sched_barrier(0);

        f32x4 accS0 = (f32x4){0.f, 0.f, 0.f, 0.f};
        f32x4 accS1 = (f32x4){0.f, 0.f, 0.f, 0.f};
        __builtin_amdgcn_s_setprio(1);
        #pragma unroll
        for (int kk = 0; kk < 8; ++kk) {
            s16x8 af = *(const s16x8*)(xbB + (kk * 2 + (g >> 1)) * 1040 +
                                       (Mt * 16 + li) * 32 + (g & 1) * 16);
            s16x8 bf0 = *(const s16x8*)(wlB + hq0 * 512 + (((kk * 4 + g) ^ (hq0 & 7)) * 16));
            s16x8 bf1 = *(const s16x8*)(wlB + hq1 * 512 + (((kk * 4 + g) ^ (hq1 & 7)) * 16));
            accS0 = __builtin_amdgcn_mfma_f32_16x16x32_bf16(af, bf0, accS0, 0, 0, 0);
            accS1 = __builtin_amdgcn_mfma_f32_16x16x32_bf16(af, bf1, accS1, 0, 0, 0);
        }
        __builtin_amdgcn_s_setprio(0);

        float aaW[4], rsv[4], rmv[4];
        #pragma unroll
        for (int r = 0; r < 4; ++r) {
            int tokr = Mt * 16 + g * 4 + r;
            rsv[r] = stats[cur][tokr];
            rmv[r] = stats[cur][32 + tokr];
            float lg0 = fmaf(rsv[r], accS0[r], fmaf(-rmv[r], c1h0, c0h0));
            float lg1 = fmaf(rsv[r], accS1[r], fmaf(-rmv[r], c1h1, c0h1));
            float v = fmaxf(lg0, lg1);
            v = fmaxf(v, __shfl_xor(v, 1, 64));
            v = fmaxf(v, __shfl_xor(v, 2, 64));
            v = fmaxf(v, __shfl_xor(v, 4, 64));
            v = fmaxf(v, __shfl_xor(v, 8, 64));
            float ex0 = exp2f(lg0 - v);
            float ex1 = exp2f(lg1 - v);
            float s = ex0 + ex1;
            s += __shfl_xor(s, 1, 64);
            s += __shfl_xor(s, 2, 64);
            s += __shfl_xor(s, 4, 64);
            s += __shfl_xor(s, 8, 64);
            float inv = 1.f / s;
            float aw = (Nt ? ex1 : ex0) * inv;
            A0acc += aw;
            A1acc = fmaf(aw, rmv[r], A1acc);
            aaW[r] = aw * rsv[r];
        }
        {
            uint2 pw;
            pw.x = pk2(aaW[0], aaW[1]);
            pw.y = pk2(aaW[2], aaW[3]);
            int tokb = Mt * 16 + g * 4;
            int slot = (tokb >> 3) ^ ((hqB >> 1) & 3);
            *(uint2*)(ptB + hqB * 64 + slot * 16 + (tokb & 7) * 2) = pw;
        }
        __syncthreads();   // D

        if (WVIS) {
            int tk = t >> 3, q = t & 7;
            float sv = 0.f;
            #pragma unroll
            for (int h = 0; h < 4; ++h) {
                int hq = h * 8 + q;
                int slot = (tk >> 3) ^ ((hq >> 1) & 3);
                sv += bf2f(*(const unsigned short*)(ptB + hq * 64 + slot * 16 + (tk & 7) * 2));
            }
            float vv = sv / stats[cur][tk];
            size_t o = ((size_t)b * NKV + n0 + tk) * 8 + q;
            out_vis[o] = vv; out_temp[o] = vv;
        }

        if (ci < NC - 1) {
            if (STATS) {
                calc_stats(ldN, &stats[nxt][0], rs_g, rm_g, b, n0 + 32, tok_s, seg8);
            } else {
                if (t < 32) stats[nxt][t] = rs_g[b * 4096 + n0 + 32 + t];
                else if (t < 64) stats[nxt][t] = rm_g[b * 4096 + n0 + 32 + t - 32];
            }
        }

        {
            s16x8 pa = *(const s16x8*)(ptB + hqA * 64 + ((g ^ ((hqA >> 1) & 3)) * 16));
            unsigned abase = xbase + g * 256 + li * 8;
            v2i t0a = tr_read(abase + (ntb + 0) * 1040);
            v2i t0b = tr_read(abase + (ntb + 0) * 1040 + 128);
            v2i t1a = tr_read(abase + (ntb + 1) * 1040);
            v2i t1b = tr_read(abase + (ntb + 1) * 1040 + 128);
            v2i t2a = tr_read(abase + (ntb + 2) * 1040);
            v2i t2b = tr_read(abase + (ntb + 2) * 1040 + 128);
            v2i t3a = tr_read(abase + (ntb + 3) * 1040);
            v2i t3b = tr_read(abase + (ntb + 3) * 1040 + 128);
            asm volatile("s_waitcnt lgkmcnt(0)" ::: "memory");
            __builtin_amdgcn_sched_barrier(0);
            __builtin_amdgcn_s_setprio(1);
            av[0] = __builtin_amdgcn_mfma_f32_16x16x32_bf16(pa, mk_frag(t0a, t0b), av[0], 0, 0, 0);
            av[1] = __builtin_amdgcn_mfma_f32_16x16x32_bf16(pa, mk_frag(t1a, t1b), av[1], 0, 0, 0);
            av[2] = __builtin_amdgcn_mfma_f32_16x16x32_bf16(pa, mk_frag(t2a, t2b), av[2], 0, 0, 0);
            av[3] = __builtin_amdgcn_mfma_f32_16x16x32_bf16(pa, mk_frag(t3a, t3b), av[3], 0, 0, 0);
            __builtin_amdgcn_s_setprio(0);
            v2i t4a = tr_read(abase + (ntb + 4) * 1040);
            v2i t4b = tr_read(abase + (ntb + 4) * 1040 + 128);
            v2i t5a = tr_read(abase + (ntb + 5) * 1040);
            v2i t5b = tr_read(abase + (ntb + 5) * 1040 + 128);
            v2i t6a = tr_read(abase + (ntb + 6) * 1040);
            v2i t6b = tr_read(abase + (ntb + 6) * 1040 + 128);
            v2i t7a = tr_read(abase + (ntb + 7) * 1040);
            v2i t7b = tr_read(abase + (ntb + 7) * 1040 + 128);
            asm volatile("s_waitcnt lgkmcnt(0)" ::: "memory");
            __builtin_amdgcn_sched_barrier(0);
            __builtin_amdgcn_s_setprio(1);
            av[4] = __builtin_amdgcn_mfma_f32_16x16x32_bf16(pa, mk_frag(t4a, t4b), av[4], 0, 0, 0);
            av[5] = __builtin_amdgcn_mfma_f32_16x16x32_bf16(pa, mk_frag(t5a, t5b), av[5], 0, 0, 0);
            av[6] = __builtin_amdgcn_mfma_f32_16x16x32_bf16(pa, mk_frag(t6a, t6b), av[6], 0, 0, 0);
            av[7] = __builtin_amdgcn_mfma_f32_16x16x32_bf16(pa, mk_frag(t7a, t7b), av[7], 0, 0, 0);
            __builtin_amdgcn_s_setprio(0);
        }
        __syncthreads();   // E

        if (ci < NC - 1) {
            pack_x(ldN, xbB, tok_s, seg8);
            __syncthreads();   // A
        }
    }

    A0acc += __shfl_xor(A0acc, 16, 64); A0acc += __shfl_xor(A0acc, 32, 64);
    A1acc += __shfl_xor(A1acc, 16, 64); A1acc += __shfl_xor(A1acc, 32, 64);
    const size_t blk = (size_t)b * KBMAX + kb;
    if (g == 0) {
        apart[blk * 128 + Mt * 64 + hqB] = A0acc;
        apart[blk * 128 + Mt * 64 + 32 + hqB] = A1acc;
    }
    {
        #pragma unroll
        for (int r = 0; r < 4; ++r) {
            int hq = MtV * 16 + g * 4 + r;
            unsigned* vp = vpart + (blk * 32 + hq) * 128 + li;
            #pragma unroll
            for (int ip = 0; ip < 4; ++ip) {
                unsigned u = pk2(av[2 * ip][r], av[2 * ip + 1][r]);
                int jp = (ntb >> 1) + ip;
                vp[jp * 16] = u;
            }
        }
    }
}

// ---------------------------------------------------------------------------
// V + A reduction: grid (32 b, 16).
template<int KBMAX>
__global__ __launch_bounds__(256) void k_vred(
    const unsigned* __restrict__ vpart, const float* __restrict__ apart,
    float* __restrict__ V_g, float* __restrict__ A0_g, float* __restrict__ A1_g)
{
    const int t = threadIdx.x;
    const int b = blockIdx.x;
    const int hq = blockIdx.y * 2 + (t >> 7);
    const int tl = t & 127;
    const unsigned* p = vpart + ((size_t)(b * KBMAX) * 32 + hq) * 128 + tl;
    float lo = 0.f, hi = 0.f;
    #pragma unroll 8
    for (int kb = 0; kb < KBMAX; ++kb) {
        unsigned u = p[(size_t)kb * 4096];
        lo += bflo(u); hi += bfhi(u);
    }
    const int jp = tl >> 4, li = tl & 15;
    float* vo = V_g + ((size_t)b * 32 + hq) * 256 + jp * 32 + li;
    vo[0]  = lo;
    vo[16] = hi;

    if (blockIdx.y == 0 && t < 64) {
        float s = 0.f;
        const float* ap = apart + (size_t)(b * KBMAX) * 128 + t;
        #pragma unroll 8
        for (int kb = 0; kb < KBMAX; ++kb)
            s += ap[(size_t)kb * 128] + ap[(size_t)kb * 128 + 64];
        if (t < 32) A0_g[b * 32 + t] = s;
        else        A1_g[b * 32 + t - 32] = s;
    }
}

// ---------------------------------------------------------------------------
// gx | gh GEMMs. grid (6, 64). chunk-0 blocks zero slot_nxt.
__global__ __launch_bounds__(256) void k_gates(
    const float* __restrict__ V_g, const float* __restrict__ A0_g,
    const float* __restrict__ A1_g,
    const float* __restrict__ g_in, const float* __restrict__ b_in,
    const float* __restrict__ slot_cur,
    const unsigned* __restrict__ WfT2, const unsigned* __restrict__ WhhT2,
    float* __restrict__ gxh, float* __restrict__ slot_nxt)
{
    __shared__ __align__(16) float aT[1024 * 4];
    const int t = threadIdx.x;
    const int rg = blockIdx.y;
    const int chunk = blockIdx.x;
    const int row0 = rg * 4;
    float acc0 = 0.f, acc1 = 0.f, acc2 = 0.f, acc3 = 0.f;

    if (chunk == 0) {
        #pragma unroll
        for (int rr = 0; rr < 4; ++rr)
            slot_nxt[(size_t)(row0 + rr) * 256 + t] = 0.f;
    }

    if (chunk < 3) {
        const int b = rg >> 1, qi0 = (rg & 1) * 4;
        const float gt = g_in[t], bt = b_in[t];
        #pragma unroll
        for (int kk = 0; kk < 4; ++kk) {
            float4 y4;
            #pragma unroll
            for (int rr = 0; rr < 4; ++rr) {
                int hq = kk * 8 + qi0 + rr;
                float A0 = A0_g[b * 32 + hq], A1 = A1_g[b * 32 + hq];
                float den = A0 + EPSR * (float)NKV;
                float vv = V_g[((size_t)b * 32 + hq) * 256 + t];
                float yv = (gt * (vv - A1) + bt * A0) / den;
                ((float*)&y4)[rr] = yv;
            }
            *(float4*)(aT + (kk * 256 + t) * 4) = y4;
        }
        __syncthreads();
        const unsigned* wp = WfT2 + chunk * 256 + t;
        #pragma unroll 4
        for (int k2 = 0; k2 < 512; ++k2) {
            unsigned wv = wp[(size_t)k2 * 768];
            float w0 = bflo(wv), w1 = bfhi(wv);
            float4 a0 = *(const float4*)(aT + 8 * k2);
            float4 a1 = *(const float4*)(aT + 8 * k2 + 4);
            acc0 = fmaf(a0.x, w0, acc0); acc0 = fmaf(a1.x, w1, acc0);
            acc1 = fmaf(a0.y, w0, acc1); acc1 = fmaf(a1.y, w1, acc1);
            acc2 = fmaf(a0.z, w0, acc2); acc2 = fmaf(a1.z, w1, acc2);
            acc3 = fmaf(a0.w, w0, acc3); acc3 = fmaf(a1.w, w1, acc3);
        }
        float* go = gxh + (size_t)row0 * 1536 + chunk * 256 + t;
        go[0] = acc0; go[1536] = acc1; go[3072] = acc2; go[4608] = acc3;
    } else {
        const int gc = chunk - 3;
        {
            float4 y4;
            #pragma unroll
            for (int rr = 0; rr < 4; ++rr)
                ((float*)&y4)[rr] = slot_cur[(size_t)(row0 + rr) * 256 + t];
            *(float4*)(aT + t * 4) = y4;
        }
        __syncthreads();
        const unsigned* wp = WhhT2 + gc * 256 + t;
        #pragma unroll 4
        for (int k2 = 0; k2 < 128; ++k2) {
            unsigned wv = wp[(size_t)k2 * 768];
            float w0 = bflo(wv), w1 = bfhi(wv);
            float4 a0 = *(const float4*)(aT + 8 * k2);
            float4 a1 = *(const float4*)(aT + 8 * k2 + 4);
            acc0 = fmaf(a0.x, w0, acc0); acc0 = fmaf(a1.x, w1, acc0);
            acc1 = fmaf(a0.y, w0, acc1); acc1 = fmaf(a1.y, w1, acc1);
            acc2 = fmaf(a0.z, w0, acc2); acc2 = fmaf(a1.z, w1, acc2);
            acc3 = fmaf(a0.w, w0, acc3); acc3 = fmaf(a1.w, w1, acc3);
        }
        float* go = gxh + (size_t)row0 * 1536 + 768 + gc * 256 + t;
        go[0] = acc0; go[1536] = acc1; go[3072] = acc2; go[4608] = acc3;
    }
}

// ---------------------------------------------------------------------------
// Fused GRU elementwise + LN + MLP(W1,relu,W2) with h1 in LDS. grid (4, 64).
__global__ __launch_bounds__(256) void k_mlp(
    const float* __restrict__ gxh, const float* __restrict__ slot_cur,
    const float* __restrict__ bih, const float* __restrict__ bhh,
    const float* __restrict__ gm, const float* __restrict__ bm,
    const unsigned* __restrict__ W1T2, const float* __restrict__ b1,
    const unsigned* __restrict__ W2T2, const float* __restrict__ b2,
    float* __restrict__ slot_nxt)
{
    __shared__ __align__(16) float mT[1024];
    __shared__ float sm_l[4][256];
    __shared__ float h1_l[4][256];
    __shared__ float lnst[8];
    const int t = threadIdx.x;
    const int rg = blockIdx.y, chunk = blockIdx.x;
    const int row0 = rg * 4;
    const int lane = t & 63, w = t >> 6;

    const float bi0 = bih[t], bi1 = bih[256 + t], bi2 = bih[512 + t];
    const float bh0 = bhh[t], bh1 = bhh[256 + t], bh2 = bhh[512 + t];
    float smid[4];
    #pragma unroll
    for (int rr = 0; rr < 4; ++rr) {
        const float* gr = gxh + (size_t)(row0 + rr) * 1536;
        float gx0 = gr[t], gx1 = gr[256 + t], gx2 = gr[512 + t];
        float gh0 = gr[768 + t], gh1 = gr[1024 + t], gh2 = gr[1280 + t];
        float spv = slot_cur[(size_t)(row0 + rr) * 256 + t];
        float r = 1.f / (1.f + __expf(-(gx0 + bi0 + gh0 + bh0)));
        float z = 1.f / (1.f + __expf(-(gx1 + bi1 + gh1 + bh1)));
        float n = tanhf(gx2 + bi2 + r * (gh2 + bh2));
        smid[rr] = (1.f - z) * n + z * spv;
        sm_l[rr][t] = smid[rr];
    }
    __syncthreads();
    {
        float4 v = *(const float4*)(&sm_l[w][lane * 4]);
        float s0 = v.x + v.y + v.z + v.w;
        float s1 = v.x * v.x + v.y * v.y + v.z * v.z + v.w * v.w;
        #pragma unroll
        for (int o = 32; o >= 1; o >>= 1) { s0 += __shfl_xor(s0, o, 64); s1 += __shfl_xor(s1, o, 64); }
        if (lane == 0) {
            float mu = s0 * (1.f / 256.f);
            lnst[w * 2] = mu;
            lnst[w * 2 + 1] = rsqrtf(s1 * (1.f / 256.f) - mu * mu + 1e-5f);
        }
    }
    __syncthreads();
    {
        const float gmt = gm[t], bmt = bm[t];
        float4 m4;
        #pragma unroll
        for (int rr = 0; rr < 4; ++rr)
            ((float*)&m4)[rr] = (smid[rr] - lnst[rr * 2]) * lnst[rr * 2 + 1] * gmt + bmt;
        *(float4*)(mT + t * 4) = m4;
    }
    __syncthreads();

    {
        float acc0 = 0.f, acc1 = 0.f, acc2 = 0.f, acc3 = 0.f;
        const unsigned* wp = W1T2 + chunk * 256 + t;
        #pragma unroll 4
        for (int k2 = 0; k2 < 128; ++k2) {
            unsigned wv = wp[(size_t)k2 * 1024];
            float w0 = bflo(wv), w1 = bfhi(wv);
            float4 a0 = *(const float4*)(mT + 8 * k2);
            float4 a1 = *(const float4*)(mT + 8 * k2 + 4);
            acc0 = fmaf(a0.x, w0, acc0); acc0 = fmaf(a1.x, w1, acc0);
            acc1 = fmaf(a0.y, w0, acc1); acc1 = fmaf(a1.y, w1, acc1);
            acc2 = fmaf(a0.z, w0, acc2); acc2 = fmaf(a1.z, w1, acc2);
            acc3 = fmaf(a0.w, w0, acc3); acc3 = fmaf(a1.w, w1, acc3);
        }
        const float b1t = b1[chunk * 256 + t];
        h1_l[0][t] = fmaxf(acc0 + b1t, 0.f);
        h1_l[1][t] = fmaxf(acc1 + b1t, 0.f);
        h1_l[2][t] = fmaxf(acc2 + b1t, 0.f);
        h1_l[3][t] = fmaxf(acc3 + b1t, 0.f);
    }
    __syncthreads();

    {
        float o0 = 0.f, o1 = 0.f, o2 = 0.f, o3 = 0.f;
        const unsigned* wp = W2T2 + (size_t)(chunk * 128) * 256 + t;
        #pragma unroll 4
        for (int k2 = 0; k2 < 128; ++k2) {
            unsigned wv = wp[(size_t)k2 * 256];
            float w0 = bflo(wv), w1 = bfhi(wv);
            float a00 = h1_l[0][2 * k2], a01 = h1_l[0][2 * k2 + 1];
            float a10 = h1_l[1][2 * k2], a11 = h1_l[1][2 * k2 + 1];
            float a20 = h1_l[2][2 * k2], a21 = h1_l[2][2 * k2 + 1];
            float a30 = h1_l[3][2 * k2], a31 = h1_l[3][2 * k2 + 1];
            o0 = fmaf(a00, w0, o0); o0 = fmaf(a01, w1, o0);
            o1 = fmaf(a10, w0, o1); o1 = fmaf(a11, w1, o1);
            o2 = fmaf(a20, w0, o2); o2 = fmaf(a21, w1, o2);
            o3 = fmaf(a30, w0, o3); o3 = fmaf(a31, w1, o3);
        }
        const float b2t = b2[t];
        float p0 = o0 + ((chunk == 0) ? smid[0] + b2t : 0.f);
        float p1 = o1 + ((chunk == 0) ? smid[1] + b2t : 0.f);
        float p2 = o2 + ((chunk == 0) ? smid[2] + b2t : 0.f);
        float p3 = o3 + ((chunk == 0) ? smid[3] + b2t : 0.f);
        atomicAdd(slot_nxt + (size_t)(row0 + 0) * 256 + t, p0);
        atomicAdd(slot_nxt + (size_t)(row0 + 1) * 256 + t, p1);
        atomicAdd(slot_nxt + (size_t)(row0 + 2) * 256 + t, p2);
        atomicAdd(slot_nxt + (size_t)(row0 + 3) * 256 + t, p3);
    }
}

// ---------------------------------------------------------------------------
extern "C" void kernel_launch(void* const* d_in, const int* in_sizes, int n_in,
                              void* d_out, int out_size, void* d_ws, size_t ws_size,
                              hipStream_t stream) {
    const float* inp     = (const float*)d_in[0];
    const float* slots0  = (const float*)d_in[1];
    const float* ln_in_g = (const float*)d_in[2];
    const float* ln_in_b = (const float*)d_in[3];
    const float* ln_s_g  = (const float*)d_in[4];
    const float* ln_s_b  = (const float*)d_in[5];
    const float* ln_m_g  = (const float*)d_in[6];
    const float* ln_m_b  = (const float*)d_in[7];
    const float* Wq  = (const float*)d_in[8];
    const float* Wk  = (const float*)d_in[9];
    const float* Wv  = (const float*)d_in[10];
    const float* Wih = (const float*)d_in[11];
    const float* Whh = (const float*)d_in[12];
    const float* bih = (const float*)d_in[13];
    const float* bhh = (const float*)d_in[14];
    const float* W1  = (const float*)d_in[15];
    const float* b1  = (const float*)d_in[16];
    const float* W2  = (const float*)d_in[17];
    const float* b2  = (const float*)d_in[18];

    float* ws = (float*)d_ws;
    float* V_g   = ws + WS_V;
    float* A0_g  = ws + WS_A0;
    float* A1_g  = ws + WS_A1;
    float* c0_g  = ws + WS_C0;
    float* c1_g  = ws + WS_C1;
    float* slotA = ws + WS_SLOTA;
    float* slotB = ws + WS_SLOTB;
    float* wqt   = ws + WS_WQT;
    float* gxh   = ws + WS_WPGXH;
    unsigned short* wp_bf = (unsigned short*)(ws + WS_WPGXH);
    unsigned* WfT2  = (unsigned*)(ws + WS_WFT);
    unsigned* WhhT2 = (unsigned*)(ws + WS_WHHT);
    unsigned* W1T2  = (unsigned*)(ws + WS_W1T);
    unsigned* W2T2  = (unsigned*)(ws + WS_W2T);
    float* rs_g  = ws + WS_RS;
    float* rm_g  = ws + WS_RM;
    unsigned* vpart = (unsigned*)(ws + WS_VPART);
    float* apart = ws + WS_APART;

    float* out_slots = (float*)d_out;
    float* out_vis   = out_slots + 32 * 8 * 256;
    float* out_temp  = out_vis + 32 * 4096 * 8;

    k_setup<<<1600, 256, 0, stream>>>(Wq, Wih, Wv, Whh, W1, W2,
                                      wqt, WfT2, WhhT2, W1T2, W2T2);

    for (int it = 0; it < 3; ++it) {
        const float* cur = (it == 0) ? slots0 : ((it == 1) ? slotB : slotA);
        float* nxt = (it == 0) ? slotB : ((it == 1) ? slotA : out_slots);
        k_prep<<<dim3(32, 4), 256, 0, stream>>>(cur, ln_s_g, ln_s_b, wqt, Wk,
                                                ln_in_g, ln_in_b, wp_bf, c0_g, c1_g);
        if (it == 0)
            k_attn<2, 1, 0><<<dim3(64, 32), 256, 0, stream>>>(
                inp, wp_bf, c0_g, c1_g, vpart, apart, rs_g, rm_g, out_vis, out_temp);
        else if (it == 1)
            k_attn<2, 0, 0><<<dim3(64, 32), 256, 0, stream>>>(
                inp, wp_bf, c0_g, c1_g, vpart, apart, rs_g, rm_g, out_vis, out_temp);
        else
            k_attn<2, 0, 1><<<dim3(64, 32), 256, 0, stream>>>(
                inp, wp_bf, c0_g, c1_g, vpart, apart, rs_g, rm_g, out_vis, out_temp);
        k_vred<64><<<dim3(32, 16), 256, 0, stream>>>(vpart, apart, V_g, A0_g, A1_g);
        k_gates<<<dim3(6, 64), 256, 0, stream>>>(
            V_g, A0_g, A1_g, ln_in_g, ln_in_b, cur, WfT2, WhhT2, gxh, nxt);
        k_mlp<<<dim3(4, 64), 256, 0, stream>>>(
            gxh, cur, bih, bhh, ln_m_g, ln_m_b, W1T2, b1, W2T2, b2, nxt);
    }
}

// Round 18
// 420.083 us; speedup vs baseline: 3.2788x; 1.0253x over previous
//
#include <hip/hip_runtime.h>
#include <math.h>

// ---------------------------------------------------------------------------
// SlotAttention fused forward. MFMA (bf16) attention path (r13 k_attn core).
//   k_setup: all weight prep in one launch.
//   k_attn: NC=4 chunks/block, grid 1024 = exactly ONE resident round at
//   4 blocks/CU (35.8KB LDS) -- halves per-block fixed overhead vs NC=2.
//   A0/A1: per-block partials (apart), V partials bf16 (vpart, 16MB) -> k_vred.
//   GRU/MLP: gx = yflat @ Wfold^T; k_gates + fused k_mlp.
// Kernel-boundary sync only (~9us); grid.sync / per-block threadfence are
// catastrophic on the 8-XCD part (r15/r16 measured).
// ---------------------------------------------------------------------------

#define NKV   4096
#define DD    256
#define HQN   32
#define EPSR  1e-8f

// workspace layout (float offsets)
#define WS_V      0                     // 262144
#define WS_A0     262144                // 1024
#define WS_A1     263168                // 1024
#define WS_C0     264192                // 1024
#define WS_C1     265216                // 1024
#define WS_SLOTA  266240                // 65536
#define WS_SLOTB  331776                // 65536
#define WS_WQT    397312                // 65536 fp32 Wq^T
#define WS_WPGXH  462848                // 393216 (wp_bf 131072f | gxh [256][1536])
#define WS_WFT    856064                // 393216 uints: WfoldT2 [512][768]
#define WS_WHHT   1249280               // 98304 uints:  WhhT2   [128][768]
#define WS_W1T    1347584               // 131072 uints: W1T2    [128][1024]
#define WS_W2T    1478656               // 131072 uints: W2T2    [512][256]
#define WS_RS     1609728               // 131072 fp32 rs per token
#define WS_RM     1740800               // 131072 fp32 rm per token
#define WS_VPART  1871872               // vpart bf16x2 (<=32MB region)
#define WS_APART  10260480              // apart[<=2048 blk][128]

typedef float f32x4 __attribute__((ext_vector_type(4)));
typedef short s16x8 __attribute__((ext_vector_type(8)));
typedef int   v2i   __attribute__((ext_vector_type(2)));

__device__ __forceinline__ unsigned bfr(float f) {
    unsigned u = __float_as_uint(f);
    return (u + 0x7fffu + ((u >> 16) & 1u)) >> 16;
}
__device__ __forceinline__ unsigned pk2(float lo, float hi) {
    return bfr(lo) | (bfr(hi) << 16);
}
__device__ __forceinline__ float bf2f(unsigned short us) {
    return __uint_as_float((unsigned)us << 16);
}
__device__ __forceinline__ float bflo(unsigned u) { return __uint_as_float(u << 16); }
__device__ __forceinline__ float bfhi(unsigned u) { return __uint_as_float(u & 0xffff0000u); }

__device__ __forceinline__ v2i tr_read(unsigned addr) {
    v2i d;
    asm volatile("ds_read_b64_tr_b16 %0, %1" : "=v"(d) : "v"(addr));
    return d;
}
__device__ __forceinline__ s16x8 mk_frag(v2i a, v2i b) {
    union { int i[4]; s16x8 s; } u;
    u.i[0] = a.x; u.i[1] = a.y; u.i[2] = b.x; u.i[3] = b.y;
    return u.s;
}

// ---------------------------------------------------------------------------
// Fused weight prep. grid 1600.
__global__ __launch_bounds__(256) void k_setup(
    const float* __restrict__ Wq, const float* __restrict__ Wih,
    const float* __restrict__ Wv, const float* __restrict__ Whh,
    const float* __restrict__ W1, const float* __restrict__ W2,
    float* __restrict__ wqt, unsigned* __restrict__ WfT2,
    unsigned* __restrict__ WhhT2, unsigned* __restrict__ W1T2,
    unsigned* __restrict__ W2T2)
{
    const int blk = blockIdx.x;
    const int t = threadIdx.x;
    if (blk < 64) {
        __shared__ float tile[32][33];
        int bx = (blk & 7) * 32, by = (blk >> 3) * 32;
        int tx = t & 31, ty = t >> 5;
        #pragma unroll
        for (int k = 0; k < 32; k += 8)
            tile[ty + k][tx] = Wq[(size_t)(by + ty + k) * 256 + bx + tx];
        __syncthreads();
        #pragma unroll
        for (int k = 0; k < 32; k += 8)
            wqt[(size_t)(bx + ty + k) * 256 + by + tx] = tile[tx][ty + k];
    } else if (blk < 832) {
        const int c = blk - 64;
        __shared__ float wr[256];
        wr[t] = Wih[(size_t)c * 256 + t];
        __syncthreads();
        const float2* wv2 = (const float2*)Wv;
        #pragma unroll
        for (int pp = 0; pp < 2; ++pp) {
            int P = pp * 256 + t;
            int h = P >> 7, p = P & 127;
            float f0 = 0.f, f1 = 0.f;
            #pragma unroll 8
            for (int d = 0; d < 64; ++d) {
                float a = wr[h * 64 + d];
                float2 v = wv2[(size_t)(h * 64 + d) * 128 + p];
                f0 = fmaf(a, v.x, f0); f1 = fmaf(a, v.y, f1);
            }
            WfT2[(size_t)P * 768 + c] = pk2(f0, f1);
        }
    } else if (blk < 960) {
        const int c2 = blk - 832;
        #pragma unroll
        for (int q = 0; q < 3; ++q) {
            int r = q * 256 + t;
            WhhT2[(size_t)c2 * 768 + r] = pk2(Whh[(size_t)r * 256 + 2 * c2],
                                              Whh[(size_t)r * 256 + 2 * c2 + 1]);
        }
    } else if (blk < 1088) {
        const int c2 = blk - 960;
        #pragma unroll
        for (int q = 0; q < 4; ++q) {
            int r = q * 256 + t;
            W1T2[(size_t)c2 * 1024 + r] = pk2(W1[(size_t)r * 256 + 2 * c2],
                                              W1[(size_t)r * 256 + 2 * c2 + 1]);
        }
    } else {
        const int c2 = blk - 1088;
        W2T2[(size_t)c2 * 256 + t] = pk2(W2[(size_t)t * 1024 + 2 * c2],
                                         W2[(size_t)t * 1024 + 2 * c2 + 1]);
    }
}

// ---------------------------------------------------------------------------
// Merged slot prep: grid (32 b, 4 h).
__global__ __launch_bounds__(256) void k_prep(
    const float* __restrict__ slots, const float* __restrict__ g_s, const float* __restrict__ b_s,
    const float* __restrict__ wqt, const float* __restrict__ Wk,
    const float* __restrict__ g_in, const float* __restrict__ b_in,
    unsigned short* __restrict__ wp_bf, float* __restrict__ c0_g, float* __restrict__ c1_g)
{
    __shared__ float s_lds[2048];
    __shared__ float qs[512];
    __shared__ float redc[4096];
    const int t = threadIdx.x;
    const int b = blockIdx.x, h = blockIdx.y;
    const int lane = t & 63, w = t >> 6;
    const float LNS = 0.125f * 1.44269504f;

    for (int r = w; r < 8; r += 4) {
        const float4 v = ((const float4*)(slots + ((size_t)b * 8 + r) * 256))[lane];
        float s0 = v.x + v.y + v.z + v.w;
        float s1 = v.x * v.x + v.y * v.y + v.z * v.z + v.w * v.w;
        #pragma unroll
        for (int o = 32; o >= 1; o >>= 1) { s0 += __shfl_xor(s0, o, 64); s1 += __shfl_xor(s1, o, 64); }
        float m = s0 * (1.f / 256.f);
        float rs = rsqrtf(s1 * (1.f / 256.f) - m * m + 1e-5f);
        float4 gg = ((const float4*)g_s)[lane];
        float4 bb = ((const float4*)b_s)[lane];
        float4 nn;
        nn.x = (v.x - m) * rs * gg.x + bb.x;
        nn.y = (v.y - m) * rs * gg.y + bb.y;
        nn.z = (v.z - m) * rs * gg.z + bb.z;
        nn.w = (v.w - m) * rs * gg.w + bb.w;
        ((float4*)(s_lds + r * 256))[lane] = nn;
    }
    __syncthreads();

    {
        const int qi0 = t >> 6, d = t & 63;
        float a0 = 0.f, a1 = 0.f;
        #pragma unroll 8
        for (int j = 0; j < 256; ++j) {
            float wv = wqt[j * 256 + h * 64 + d];
            a0 = fmaf(s_lds[qi0 * 256 + j], wv, a0);
            a1 = fmaf(s_lds[(qi0 + 4) * 256 + j], wv, a1);
        }
        qs[qi0 * 64 + d] = a0;
        qs[(qi0 + 4) * 64 + d] = a1;
    }
    __syncthreads();

    float a2[8];
    #pragma unroll
    for (int qi = 0; qi < 8; ++qi) a2[qi] = 0.f;
    #pragma unroll 4
    for (int d = 0; d < 64; ++d) {
        float wv = Wk[(size_t)(h * 64 + d) * 256 + t];
        #pragma unroll
        for (int qi = 0; qi < 8; ++qi) a2[qi] = fmaf(qs[qi * 64 + d], wv, a2[qi]);
    }
    const float gv = g_in[t], bv = b_in[t];
    #pragma unroll
    for (int qi = 0; qi < 8; ++qi) {
        float kv = LNS * a2[qi];
        float we = kv * gv;
        wp_bf[((size_t)b * HQN + h * 8 + qi) * 256 + t] = (unsigned short)bfr(we);
        redc[qi * 256 + t] = we;
        redc[2048 + qi * 256 + t] = kv * bv;
    }
    __syncthreads();
    #pragma unroll
    for (int rep = 0; rep < 2; ++rep) {
        int r = w * 2 + rep;
        float sv1 = redc[r * 256 + lane] + redc[r * 256 + 64 + lane] +
                    redc[r * 256 + 128 + lane] + redc[r * 256 + 192 + lane];
        float sv0 = redc[2048 + r * 256 + lane] + redc[2048 + r * 256 + 64 + lane] +
                    redc[2048 + r * 256 + 128 + lane] + redc[2048 + r * 256 + 192 + lane];
        #pragma unroll
        for (int o = 32; o >= 1; o >>= 1) {
            sv1 += __shfl_xor(sv1, o, 64);
            sv0 += __shfl_xor(sv0, o, 64);
        }
        if (lane == 0) {
            c1_g[b * 32 + h * 8 + r] = sv1;
            c0_g[b * 32 + h * 8 + r] = sv0;
        }
    }
}

// ---------------------------------------------------------------------------
// k_attn helpers
__device__ __forceinline__ void load_x(const float* __restrict__ inp, int b, int n0,
                                       int tok_s, int seg8, float4* ld) {
    const float4* row4 = (const float4*)(inp + ((size_t)b * NKV + n0 + tok_s) * 256);
    #pragma unroll
    for (int u = 0; u < 8; ++u) ld[u] = row4[(u >> 2) * 32 + seg8 * 4 + (u & 3)];
}

__device__ __forceinline__ void pack_x(const float4* ld, char* dst, int tok_s, int seg8) {
    #pragma unroll
    for (int c = 0; c < 2; ++c) {
        int nt = seg8 + 8 * c;
        #pragma unroll
        for (int h = 0; h < 2; ++h) {
            float4 fa = ld[c * 4 + h * 2], fb = ld[c * 4 + h * 2 + 1];
            uint4 pk;
            pk.x = pk2(fa.x, fa.y); pk.y = pk2(fa.z, fa.w);
            pk.z = pk2(fb.x, fb.y); pk.w = pk2(fb.z, fb.w);
            *(uint4*)(dst + nt * 1040 + tok_s * 32 + h * 16) = pk;
        }
    }
}

__device__ __forceinline__ void calc_stats(const float4* ld, float* sb,
                                           float* __restrict__ rs_g, float* __restrict__ rm_g,
                                           int b, int n0, int tok_s, int seg8) {
    float s0 = 0.f, s1 = 0.f;
    #pragma unroll
    for (int u = 0; u < 8; ++u) {
        float4 v = ld[u];
        s0 += v.x + v.y + v.z + v.w;
        s1 = fmaf(v.x, v.x, s1); s1 = fmaf(v.y, v.y, s1);
        s1 = fmaf(v.z, v.z, s1); s1 = fmaf(v.w, v.w, s1);
    }
    s0 += __shfl_xor(s0, 1, 64); s1 += __shfl_xor(s1, 1, 64);
    s0 += __shfl_xor(s0, 2, 64); s1 += __shfl_xor(s1, 2, 64);
    s0 += __shfl_xor(s0, 4, 64); s1 += __shfl_xor(s1, 4, 64);
    float m  = s0 * (1.f / 256.f);
    float rs = rsqrtf(s1 * (1.f / 256.f) - m * m + 1e-5f);
    if (seg8 == 0) {
        sb[tok_s] = rs;
        sb[32 + tok_s] = rs * m;
        rs_g[b * 4096 + n0 + tok_s] = rs;
        rm_g[b * 4096 + n0 + tok_s] = rs * m;
    }
}

// ---------------------------------------------------------------------------
// Main fused MFMA pass (r13 structure). grid (128/NC, 32).
template<int NC, int STATS, int WVIS>
__global__ __launch_bounds__(256) void k_attn(
    const float* __restrict__ inp, const unsigned short* __restrict__ wp_bf,
    const float* __restrict__ c0_g, const float* __restrict__ c1_g,
    unsigned* __restrict__ vpart, float* __restrict__ apart,
    float* __restrict__ rs_g, float* __restrict__ rm_g,
    float* __restrict__ out_vis, float* __restrict__ out_temp)
{
    constexpr int KBMAX = 128 / NC;
    __shared__ unsigned short xb[8320];
    __shared__ unsigned short wl[8192];
    __shared__ unsigned short pt[1024];
    __shared__ float stats[2][64];

    const int t = threadIdx.x;
    const int l = t & 63, w = t >> 6;
    const int g = l >> 4, li = l & 15;
    const int b = blockIdx.y, kb = blockIdx.x;

    char* xbB = (char*)xb;
    char* wlB = (char*)wl;
    char* ptB = (char*)pt;
    const int tok_s = t >> 3, seg8 = t & 7;
    const int cbase = kb * NC;

    {
        const uint4* wp4 = (const uint4*)wp_bf + ((size_t)b * 8192 + (t >> 3) * 256 + (t & 7) * 32) / 8;
        const int hq = t >> 3, sg = t & 7;
        #pragma unroll
        for (int q = 0; q < 4; ++q) {
            uint4 v = wp4[q];
            *(uint4*)(wlB + hq * 512 + (((sg * 4 + q) ^ (hq & 7)) * 16)) = v;
        }
    }

    const int Mt = w & 1, Nt = w >> 1;
    const int hqB = Nt * 16 + li;
    const int hq0 = li, hq1 = 16 + li;
    const float c0h0 = c0_g[b * 32 + hq0], c1h0 = c1_g[b * 32 + hq0];
    const float c0h1 = c0_g[b * 32 + hq1], c1h1 = c1_g[b * 32 + hq1];
    const int MtV = w >> 1, ntb = (w & 1) * 8;
    const int hqA = MtV * 16 + li;

    f32x4 av[8];
    #pragma unroll
    for (int u = 0; u < 8; ++u) av[u] = (f32x4){0.f, 0.f, 0.f, 0.f};
    float A0acc = 0.f, A1acc = 0.f;

    const unsigned xbase = (unsigned)(uintptr_t)xbB;

    {
        float4 ldA[8];
        load_x(inp, b, cbase * 32, tok_s, seg8, ldA);
        if (STATS) {
            calc_stats(ldA, &stats[0][0], rs_g, rm_g, b, cbase * 32, tok_s, seg8);
        } else {
            if (t < 32) stats[0][t] = rs_g[b * 4096 + cbase * 32 + t];
            else if (t < 64) stats[0][t] = rm_g[b * 4096 + cbase * 32 + t - 32];
        }
        pack_x(ldA, xbB, tok_s, seg8);
    }
    __syncthreads();   // A

    #pragma unroll
    for (int ci = 0; ci < NC; ++ci) {
        const int cur = ci & 1, nxt = cur ^ 1;
        const int n0 = (cbase + ci) * 32;

        float4 ldN[8];
        if (ci < NC - 1) load_x(inp, b, n0 + 32, tok_s, seg8, ldN);
        __builtin_amdgcn_sched_barrier(0);

        f32x4 accS0 = (f32x4){0.f, 0.f, 0.f, 0.f};
        f32x4 accS1 = (f32x4){0.f, 0.f, 0.f, 0.f};
        __builtin_amdgcn_s_setprio(1);
        #pragma unroll
        for (int kk = 0; kk < 8; ++kk) {
            s16x8 af = *(const s16x8*)(xbB + (kk * 2 + (g >> 1)) * 1040 +
                                       (Mt * 16 + li) * 32 + (g & 1) * 16);
            s16x8 bf0 = *(const s16x8*)(wlB + hq0 * 512 + (((kk * 4 + g) ^ (hq0 & 7)) * 16));
            s16x8 bf1 = *(const s16x8*)(wlB + hq1 * 512 + (((kk * 4 + g) ^ (hq1 & 7)) * 16));
            accS0 = __builtin_amdgcn_mfma_f32_16x16x32_bf16(af, bf0, accS0, 0, 0, 0);
            accS1 = __builtin_amdgcn_mfma_f32_16x16x32_bf16(af, bf1, accS1, 0, 0, 0);
        }
        __builtin_amdgcn_s_setprio(0);

        float aaW[4], rsv[4], rmv[4];
        #pragma unroll
        for (int r = 0; r < 4; ++r) {
            int tokr = Mt * 16 + g * 4 + r;
            rsv[r] = stats[cur][tokr];
            rmv[r] = stats[cur][32 + tokr];
            float lg0 = fmaf(rsv[r], accS0[r], fmaf(-rmv[r], c1h0, c0h0));
            float lg1 = fmaf(rsv[r], accS1[r], fmaf(-rmv[r], c1h1, c0h1));
            float v = fmaxf(lg0, lg1);
            v = fmaxf(v, __shfl_xor(v, 1, 64));
            v = fmaxf(v, __shfl_xor(v, 2, 64));
            v = fmaxf(v, __shfl_xor(v, 4, 64));
            v = fmaxf(v, __shfl_xor(v, 8, 64));
            float ex0 = exp2f(lg0 - v);
            float ex1 = exp2f(lg1 - v);
            float s = ex0 + ex1;
            s += __shfl_xor(s, 1, 64);
            s += __shfl_xor(s, 2, 64);
            s += __shfl_xor(s, 4, 64);
            s += __shfl_xor(s, 8, 64);
            float inv = 1.f / s;
            float aw = (Nt ? ex1 : ex0) * inv;
            A0acc += aw;
            A1acc = fmaf(aw, rmv[r], A1acc);
            aaW[r] = aw * rsv[r];
        }
        {
            uint2 pw;
            pw.x = pk2(aaW[0], aaW[1]);
            pw.y = pk2(aaW[2], aaW[3]);
            int tokb = Mt * 16 + g * 4;
            int slot = (tokb >> 3) ^ ((hqB >> 1) & 3);
            *(uint2*)(ptB + hqB * 64 + slot * 16 + (tokb & 7) * 2) = pw;
        }
        __syncthreads();   // D

        if (WVIS) {
            int tk = t >> 3, q = t & 7;
            float sv = 0.f;
            #pragma unroll
            for (int h = 0; h < 4; ++h) {
                int hq = h * 8 + q;
                int slot = (tk >> 3) ^ ((hq >> 1) & 3);
                sv += bf2f(*(const unsigned short*)(ptB + hq * 64 + slot * 16 + (tk & 7) * 2));
            }
            float vv = sv / stats[cur][tk];
            size_t o = ((size_t)b * NKV + n0 + tk) * 8 + q;
            out_vis[o] = vv; out_temp[o] = vv;
        }

        if (ci < NC - 1) {
            if (STATS) {
                calc_stats(ldN, &stats[nxt][0], rs_g, rm_g, b, n0 + 32, tok_s, seg8);
            } else {
                if (t < 32) stats[nxt][t] = rs_g[b * 4096 + n0 + 32 + t];
                else if (t < 64) stats[nxt][t] = rm_g[b * 4096 + n0 + 32 + t - 32];
            }
        }

        {
            s16x8 pa = *(const s16x8*)(ptB + hqA * 64 + ((g ^ ((hqA >> 1) & 3)) * 16));
            unsigned abase = xbase + g * 256 + li * 8;
            v2i t0a = tr_read(abase + (ntb + 0) * 1040);
            v2i t0b = tr_read(abase + (ntb + 0) * 1040 + 128);
            v2i t1a = tr_read(abase + (ntb + 1) * 1040);
            v2i t1b = tr_read(abase + (ntb + 1) * 1040 + 128);
            v2i t2a = tr_read(abase + (ntb + 2) * 1040);
            v2i t2b = tr_read(abase + (ntb + 2) * 1040 + 128);
            v2i t3a = tr_read(abase + (ntb + 3) * 1040);
            v2i t3b = tr_read(abase + (ntb + 3) * 1040 + 128);
            asm volatile("s_waitcnt lgkmcnt(0)" ::: "memory");
            __builtin_amdgcn_sched_barrier(0);
            __builtin_amdgcn_s_setprio(1);
            av[0] = __builtin_amdgcn_mfma_f32_16x16x32_bf16(pa, mk_frag(t0a, t0b), av[0], 0, 0, 0);
            av[1] = __builtin_amdgcn_mfma_f32_16x16x32_bf16(pa, mk_frag(t1a, t1b), av[1], 0, 0, 0);
            av[2] = __builtin_amdgcn_mfma_f32_16x16x32_bf16(pa, mk_frag(t2a, t2b), av[2], 0, 0, 0);
            av[3] = __builtin_amdgcn_mfma_f32_16x16x32_bf16(pa, mk_frag(t3a, t3b), av[3], 0, 0, 0);
            __builtin_amdgcn_s_setprio(0);
            v2i t4a = tr_read(abase + (ntb + 4) * 1040);
            v2i t4b = tr_read(abase + (ntb + 4) * 1040 + 128);
            v2i t5a = tr_read(abase + (ntb + 5) * 1040);
            v2i t5b = tr_read(abase + (ntb + 5) * 1040 + 128);
            v2i t6a = tr_read(abase + (ntb + 6) * 1040);
            v2i t6b = tr_read(abase + (ntb + 6) * 1040 + 128);
            v2i t7a = tr_read(abase + (ntb + 7) * 1040);
            v2i t7b = tr_read(abase + (ntb + 7) * 1040 + 128);
            asm volatile("s_waitcnt lgkmcnt(0)" ::: "memory");
            __builtin_amdgcn_sched_barrier(0);
            __builtin_amdgcn_s_setprio(1);
            av[4] = __builtin_amdgcn_mfma_f32_16x16x32_bf16(pa, mk_frag(t4a, t4b), av[4], 0, 0, 0);
            av[5] = __builtin_amdgcn_mfma_f32_16x16x32_bf16(pa, mk_frag(t5a, t5b), av[5], 0, 0, 0);
            av[6] = __builtin_amdgcn_mfma_f32_16x16x32_bf16(pa, mk_frag(t6a, t6b), av[6], 0, 0, 0);
            av[7] = __builtin_amdgcn_mfma_f32_16x16x32_bf16(pa, mk_frag(t7a, t7b), av[7], 0, 0, 0);
            __builtin_amdgcn_s_setprio(0);
        }
        __syncthreads();   // E

        if (ci < NC - 1) {
            pack_x(ldN, xbB, tok_s, seg8);
            __syncthreads();   // A
        }
    }

    A0acc += __shfl_xor(A0acc, 16, 64); A0acc += __shfl_xor(A0acc, 32, 64);
    A1acc += __shfl_xor(A1acc, 16, 64); A1acc += __shfl_xor(A1acc, 32, 64);
    const size_t blk = (size_t)b * KBMAX + kb;
    if (g == 0) {
        apart[blk * 128 + Mt * 64 + hqB] = A0acc;
        apart[blk * 128 + Mt * 64 + 32 + hqB] = A1acc;
    }
    {
        #pragma unroll
        for (int r = 0; r < 4; ++r) {
            int hq = MtV * 16 + g * 4 + r;
            unsigned* vp = vpart + (blk * 32 + hq) * 128 + li;
            #pragma unroll
            for (int ip = 0; ip < 4; ++ip) {
                unsigned u = pk2(av[2 * ip][r], av[2 * ip + 1][r]);
                int jp = (ntb >> 1) + ip;
                vp[jp * 16] = u;
            }
        }
    }
}

// ---------------------------------------------------------------------------
// V + A reduction: grid (32 b, 16).
template<int KBMAX>
__global__ __launch_bounds__(256) void k_vred(
    const unsigned* __restrict__ vpart, const float* __restrict__ apart,
    float* __restrict__ V_g, float* __restrict__ A0_g, float* __restrict__ A1_g)
{
    const int t = threadIdx.x;
    const int b = blockIdx.x;
    const int hq = blockIdx.y * 2 + (t >> 7);
    const int tl = t & 127;
    const unsigned* p = vpart + ((size_t)(b * KBMAX) * 32 + hq) * 128 + tl;
    float lo = 0.f, hi = 0.f;
    #pragma unroll 8
    for (int kb = 0; kb < KBMAX; ++kb) {
        unsigned u = p[(size_t)kb * 4096];
        lo += bflo(u); hi += bfhi(u);
    }
    const int jp = tl >> 4, li = tl & 15;
    float* vo = V_g + ((size_t)b * 32 + hq) * 256 + jp * 32 + li;
    vo[0]  = lo;
    vo[16] = hi;

    if (blockIdx.y == 0 && t < 64) {
        float s = 0.f;
        const float* ap = apart + (size_t)(b * KBMAX) * 128 + t;
        #pragma unroll 8
        for (int kb = 0; kb < KBMAX; ++kb)
            s += ap[(size_t)kb * 128] + ap[(size_t)kb * 128 + 64];
        if (t < 32) A0_g[b * 32 + t] = s;
        else        A1_g[b * 32 + t - 32] = s;
    }
}

// ---------------------------------------------------------------------------
// gx | gh GEMMs. grid (6, 64). chunk-0 blocks zero slot_nxt.
__global__ __launch_bounds__(256) void k_gates(
    const float* __restrict__ V_g, const float* __restrict__ A0_g,
    const float* __restrict__ A1_g,
    const float* __restrict__ g_in, const float* __restrict__ b_in,
    const float* __restrict__ slot_cur,
    const unsigned* __restrict__ WfT2, const unsigned* __restrict__ WhhT2,
    float* __restrict__ gxh, float* __restrict__ slot_nxt)
{
    __shared__ __align__(16) float aT[1024 * 4];
    const int t = threadIdx.x;
    const int rg = blockIdx.y;
    const int chunk = blockIdx.x;
    const int row0 = rg * 4;
    float acc0 = 0.f, acc1 = 0.f, acc2 = 0.f, acc3 = 0.f;

    if (chunk == 0) {
        #pragma unroll
        for (int rr = 0; rr < 4; ++rr)
            slot_nxt[(size_t)(row0 + rr) * 256 + t] = 0.f;
    }

    if (chunk < 3) {
        const int b = rg >> 1, qi0 = (rg & 1) * 4;
        const float gt = g_in[t], bt = b_in[t];
        #pragma unroll
        for (int kk = 0; kk < 4; ++kk) {
            float4 y4;
            #pragma unroll
            for (int rr = 0; rr < 4; ++rr) {
                int hq = kk * 8 + qi0 + rr;
                float A0 = A0_g[b * 32 + hq], A1 = A1_g[b * 32 + hq];
                float den = A0 + EPSR * (float)NKV;
                float vv = V_g[((size_t)b * 32 + hq) * 256 + t];
                float yv = (gt * (vv - A1) + bt * A0) / den;
                ((float*)&y4)[rr] = yv;
            }
            *(float4*)(aT + (kk * 256 + t) * 4) = y4;
        }
        __syncthreads();
        const unsigned* wp = WfT2 + chunk * 256 + t;
        #pragma unroll 4
        for (int k2 = 0; k2 < 512; ++k2) {
            unsigned wv = wp[(size_t)k2 * 768];
            float w0 = bflo(wv), w1 = bfhi(wv);
            float4 a0 = *(const float4*)(aT + 8 * k2);
            float4 a1 = *(const float4*)(aT + 8 * k2 + 4);
            acc0 = fmaf(a0.x, w0, acc0); acc0 = fmaf(a1.x, w1, acc0);
            acc1 = fmaf(a0.y, w0, acc1); acc1 = fmaf(a1.y, w1, acc1);
            acc2 = fmaf(a0.z, w0, acc2); acc2 = fmaf(a1.z, w1, acc2);
            acc3 = fmaf(a0.w, w0, acc3); acc3 = fmaf(a1.w, w1, acc3);
        }
        float* go = gxh + (size_t)row0 * 1536 + chunk * 256 + t;
        go[0] = acc0; go[1536] = acc1; go[3072] = acc2; go[4608] = acc3;
    } else {
        const int gc = chunk - 3;
        {
            float4 y4;
            #pragma unroll
            for (int rr = 0; rr < 4; ++rr)
                ((float*)&y4)[rr] = slot_cur[(size_t)(row0 + rr) * 256 + t];
            *(float4*)(aT + t * 4) = y4;
        }
        __syncthreads();
        const unsigned* wp = WhhT2 + gc * 256 + t;
        #pragma unroll 4
        for (int k2 = 0; k2 < 128; ++k2) {
            unsigned wv = wp[(size_t)k2 * 768];
            float w0 = bflo(wv), w1 = bfhi(wv);
            float4 a0 = *(const float4*)(aT + 8 * k2);
            float4 a1 = *(const float4*)(aT + 8 * k2 + 4);
            acc0 = fmaf(a0.x, w0, acc0); acc0 = fmaf(a1.x, w1, acc0);
            acc1 = fmaf(a0.y, w0, acc1); acc1 = fmaf(a1.y, w1, acc1);
            acc2 = fmaf(a0.z, w0, acc2); acc2 = fmaf(a1.z, w1, acc2);
            acc3 = fmaf(a0.w, w0, acc3); acc3 = fmaf(a1.w, w1, acc3);
        }
        float* go = gxh + (size_t)row0 * 1536 + 768 + gc * 256 + t;
        go[0] = acc0; go[1536] = acc1; go[3072] = acc2; go[4608] = acc3;
    }
}

// ---------------------------------------------------------------------------
// Fused GRU elementwise + LN + MLP(W1,relu,W2) with h1 in LDS. grid (4, 64).
__global__ __launch_bounds__(256) void k_mlp(
    const float* __restrict__ gxh, const float* __restrict__ slot_cur,
    const float* __restrict__ bih, const float* __restrict__ bhh,
    const float* __restrict__ gm, const float* __restrict__ bm,
    const unsigned* __restrict__ W1T2, const float* __restrict__ b1,
    const unsigned* __restrict__ W2T2, const float* __restrict__ b2,
    float* __restrict__ slot_nxt)
{
    __shared__ __align__(16) float mT[1024];
    __shared__ float sm_l[4][256];
    __shared__ float h1_l[4][256];
    __shared__ float lnst[8];
    const int t = threadIdx.x;
    const int rg = blockIdx.y, chunk = blockIdx.x;
    const int row0 = rg * 4;
    const int lane = t & 63, w = t >> 6;

    const float bi0 = bih[t], bi1 = bih[256 + t], bi2 = bih[512 + t];
    const float bh0 = bhh[t], bh1 = bhh[256 + t], bh2 = bhh[512 + t];
    float smid[4];
    #pragma unroll
    for (int rr = 0; rr < 4; ++rr) {
        const float* gr = gxh + (size_t)(row0 + rr) * 1536;
        float gx0 = gr[t], gx1 = gr[256 + t], gx2 = gr[512 + t];
        float gh0 = gr[768 + t], gh1 = gr[1024 + t], gh2 = gr[1280 + t];
        float spv = slot_cur[(size_t)(row0 + rr) * 256 + t];
        float r = 1.f / (1.f + __expf(-(gx0 + bi0 + gh0 + bh0)));
        float z = 1.f / (1.f + __expf(-(gx1 + bi1 + gh1 + bh1)));
        float n = tanhf(gx2 + bi2 + r * (gh2 + bh2));
        smid[rr] = (1.f - z) * n + z * spv;
        sm_l[rr][t] = smid[rr];
    }
    __syncthreads();
    {
        float4 v = *(const float4*)(&sm_l[w][lane * 4]);
        float s0 = v.x + v.y + v.z + v.w;
        float s1 = v.x * v.x + v.y * v.y + v.z * v.z + v.w * v.w;
        #pragma unroll
        for (int o = 32; o >= 1; o >>= 1) { s0 += __shfl_xor(s0, o, 64); s1 += __shfl_xor(s1, o, 64); }
        if (lane == 0) {
            float mu = s0 * (1.f / 256.f);
            lnst[w * 2] = mu;
            lnst[w * 2 + 1] = rsqrtf(s1 * (1.f / 256.f) - mu * mu + 1e-5f);
        }
    }
    __syncthreads();
    {
        const float gmt = gm[t], bmt = bm[t];
        float4 m4;
        #pragma unroll
        for (int rr = 0; rr < 4; ++rr)
            ((float*)&m4)[rr] = (smid[rr] - lnst[rr * 2]) * lnst[rr * 2 + 1] * gmt + bmt;
        *(float4*)(mT + t * 4) = m4;
    }
    __syncthreads();

    {
        float acc0 = 0.f, acc1 = 0.f, acc2 = 0.f, acc3 = 0.f;
        const unsigned* wp = W1T2 + chunk * 256 + t;
        #pragma unroll 4
        for (int k2 = 0; k2 < 128; ++k2) {
            unsigned wv = wp[(size_t)k2 * 1024];
            float w0 = bflo(wv), w1 = bfhi(wv);
            float4 a0 = *(const float4*)(mT + 8 * k2);
            float4 a1 = *(const float4*)(mT + 8 * k2 + 4);
            acc0 = fmaf(a0.x, w0, acc0); acc0 = fmaf(a1.x, w1, acc0);
            acc1 = fmaf(a0.y, w0, acc1); acc1 = fmaf(a1.y, w1, acc1);
            acc2 = fmaf(a0.z, w0, acc2); acc2 = fmaf(a1.z, w1, acc2);
            acc3 = fmaf(a0.w, w0, acc3); acc3 = fmaf(a1.w, w1, acc3);
        }
        const float b1t = b1[chunk * 256 + t];
        h1_l[0][t] = fmaxf(acc0 + b1t, 0.f);
        h1_l[1][t] = fmaxf(acc1 + b1t, 0.f);
        h1_l[2][t] = fmaxf(acc2 + b1t, 0.f);
        h1_l[3][t] = fmaxf(acc3 + b1t, 0.f);
    }
    __syncthreads();

    {
        float o0 = 0.f, o1 = 0.f, o2 = 0.f, o3 = 0.f;
        const unsigned* wp = W2T2 + (size_t)(chunk * 128) * 256 + t;
        #pragma unroll 4
        for (int k2 = 0; k2 < 128; ++k2) {
            unsigned wv = wp[(size_t)k2 * 256];
            float w0 = bflo(wv), w1 = bfhi(wv);
            float a00 = h1_l[0][2 * k2], a01 = h1_l[0][2 * k2 + 1];
            float a10 = h1_l[1][2 * k2], a11 = h1_l[1][2 * k2 + 1];
            float a20 = h1_l[2][2 * k2], a21 = h1_l[2][2 * k2 + 1];
            float a30 = h1_l[3][2 * k2], a31 = h1_l[3][2 * k2 + 1];
            o0 = fmaf(a00, w0, o0); o0 = fmaf(a01, w1, o0);
            o1 = fmaf(a10, w0, o1); o1 = fmaf(a11, w1, o1);
            o2 = fmaf(a20, w0, o2); o2 = fmaf(a21, w1, o2);
            o3 = fmaf(a30, w0, o3); o3 = fmaf(a31, w1, o3);
        }
        const float b2t = b2[t];
        float p0 = o0 + ((chunk == 0) ? smid[0] + b2t : 0.f);
        float p1 = o1 + ((chunk == 0) ? smid[1] + b2t : 0.f);
        float p2 = o2 + ((chunk == 0) ? smid[2] + b2t : 0.f);
        float p3 = o3 + ((chunk == 0) ? smid[3] + b2t : 0.f);
        atomicAdd(slot_nxt + (size_t)(row0 + 0) * 256 + t, p0);
        atomicAdd(slot_nxt + (size_t)(row0 + 1) * 256 + t, p1);
        atomicAdd(slot_nxt + (size_t)(row0 + 2) * 256 + t, p2);
        atomicAdd(slot_nxt + (size_t)(row0 + 3) * 256 + t, p3);
    }
}

// ---------------------------------------------------------------------------
extern "C" void kernel_launch(void* const* d_in, const int* in_sizes, int n_in,
                              void* d_out, int out_size, void* d_ws, size_t ws_size,
                              hipStream_t stream) {
    const float* inp     = (const float*)d_in[0];
    const float* slots0  = (const float*)d_in[1];
    const float* ln_in_g = (const float*)d_in[2];
    const float* ln_in_b = (const float*)d_in[3];
    const float* ln_s_g  = (const float*)d_in[4];
    const float* ln_s_b  = (const float*)d_in[5];
    const float* ln_m_g  = (const float*)d_in[6];
    const float* ln_m_b  = (const float*)d_in[7];
    const float* Wq  = (const float*)d_in[8];
    const float* Wk  = (const float*)d_in[9];
    const float* Wv  = (const float*)d_in[10];
    const float* Wih = (const float*)d_in[11];
    const float* Whh = (const float*)d_in[12];
    const float* bih = (const float*)d_in[13];
    const float* bhh = (const float*)d_in[14];
    const float* W1  = (const float*)d_in[15];
    const float* b1  = (const float*)d_in[16];
    const float* W2  = (const float*)d_in[17];
    const float* b2  = (const float*)d_in[18];

    float* ws = (float*)d_ws;
    float* V_g   = ws + WS_V;
    float* A0_g  = ws + WS_A0;
    float* A1_g  = ws + WS_A1;
    float* c0_g  = ws + WS_C0;
    float* c1_g  = ws + WS_C1;
    float* slotA = ws + WS_SLOTA;
    float* slotB = ws + WS_SLOTB;
    float* wqt   = ws + WS_WQT;
    float* gxh   = ws + WS_WPGXH;
    unsigned short* wp_bf = (unsigned short*)(ws + WS_WPGXH);
    unsigned* WfT2  = (unsigned*)(ws + WS_WFT);
    unsigned* WhhT2 = (unsigned*)(ws + WS_WHHT);
    unsigned* W1T2  = (unsigned*)(ws + WS_W1T);
    unsigned* W2T2  = (unsigned*)(ws + WS_W2T);
    float* rs_g  = ws + WS_RS;
    float* rm_g  = ws + WS_RM;
    unsigned* vpart = (unsigned*)(ws + WS_VPART);
    float* apart = ws + WS_APART;

    float* out_slots = (float*)d_out;
    float* out_vis   = out_slots + 32 * 8 * 256;
    float* out_temp  = out_vis + 32 * 4096 * 8;

    k_setup<<<1600, 256, 0, stream>>>(Wq, Wih, Wv, Whh, W1, W2,
                                      wqt, WfT2, WhhT2, W1T2, W2T2);

    for (int it = 0; it < 3; ++it) {
        const float* cur = (it == 0) ? slots0 : ((it == 1) ? slotB : slotA);
        float* nxt = (it == 0) ? slotB : ((it == 1) ? slotA : out_slots);
        k_prep<<<dim3(32, 4), 256, 0, stream>>>(cur, ln_s_g, ln_s_b, wqt, Wk,
                                                ln_in_g, ln_in_b, wp_bf, c0_g, c1_g);
        if (it == 0)
            k_attn<4, 1, 0><<<dim3(32, 32), 256, 0, stream>>>(
                inp, wp_bf, c0_g, c1_g, vpart, apart, rs_g, rm_g, out_vis, out_temp);
        else if (it == 1)
            k_attn<4, 0, 0><<<dim3(32, 32), 256, 0, stream>>>(
                inp, wp_bf, c0_g, c1_g, vpart, apart, rs_g, rm_g, out_vis, out_temp);
        else
            k_attn<4, 0, 1><<<dim3(32, 32), 256, 0, stream>>>(
                inp, wp_bf, c0_g, c1_g, vpart, apart, rs_g, rm_g, out_vis, out_temp);
        k_vred<32><<<dim3(32, 16), 256, 0, stream>>>(vpart, apart, V_g, A0_g, A1_g);
        k_gates<<<dim3(6, 64), 256, 0, stream>>>(
            V_g, A0_g, A1_g, ln_in_g, ln_in_b, cur, WfT2, WhhT2, gxh, nxt);
        k_mlp<<<dim3(4, 64), 256, 0, stream>>>(
            gxh, cur, bih, bhh, ln_m_g, ln_m_b, W1T2, b1, W2T2, b2, nxt);
    }
}